// Round 1
// baseline (6057.351 us; speedup 1.0000x reference)
//
#include <hip/hip_runtime.h>

__device__ __forceinline__ float lrelu(float v) { return v >= 0.0f ? v : 0.01f * v; }

// ---------------- degree ----------------
__global__ __launch_bounds__(256) void k_deg(const int* __restrict__ col,
                                             float* __restrict__ deg, int E) {
  int e = blockIdx.x * 256 + threadIdx.x;
  if (e < E) atomicAdd(&deg[col[e]], 1.0f);
}

// deg -> dinv = rsqrt(deg + 1)   (+1 = self loop)
__global__ __launch_bounds__(256) void k_dinv(float* __restrict__ deg, int N) {
  int i = blockIdx.x * 256 + threadIdx.x;
  if (i < N) deg[i] = rsqrtf(deg[i] + 1.0f);
}

// ---------------- GEMM: Y[N,128] = X[N,K] @ W[K,128] ----------------
// 256 threads/block, 32 rows/block, X tile in LDS, W streamed from L2.
template <int K>
__global__ __launch_bounds__(256) void k_gemm(const float* __restrict__ X,
                                              const float* __restrict__ W,
                                              float* __restrict__ Y, int N) {
  __shared__ float Xs[32 * K];
  const int t = threadIdx.x;
  const int row0 = blockIdx.x * 32;
  for (int i = t; i < 32 * K; i += 256) {
    int r = i / K, k = i - r * K;
    int gr = row0 + r;
    Xs[i] = (gr < N) ? X[(size_t)gr * K + k] : 0.0f;
  }
  __syncthreads();
  const int f = t & 127;
  const int rh = t >> 7;  // wave-uniform
  float acc[16];
#pragma unroll
  for (int r = 0; r < 16; ++r) acc[r] = 0.0f;
  for (int k4 = 0; k4 < K; k4 += 4) {
    float w0 = W[(k4 + 0) * 128 + f];
    float w1 = W[(k4 + 1) * 128 + f];
    float w2 = W[(k4 + 2) * 128 + f];
    float w3 = W[(k4 + 3) * 128 + f];
#pragma unroll
    for (int r = 0; r < 16; ++r) {
      float4 xv = *(const float4*)&Xs[(rh * 16 + r) * K + k4];  // broadcast b128
      acc[r] += xv.x * w0 + xv.y * w1 + xv.z * w2 + xv.w * w3;
    }
  }
#pragma unroll
  for (int r = 0; r < 16; ++r) {
    int gr = row0 + rh * 16 + r;
    if (gr < N) Y[(size_t)gr * 128 + f] = acc[r];
  }
}

// ---------------- edge scatter: A[c] += H[r] * dinv[r]*dinv[c] ----------------
// 32 threads per edge, 4 feats/thread (float4 gather + 4 atomics)
__global__ __launch_bounds__(256) void k_scatter(const int* __restrict__ row,
                                                 const int* __restrict__ col,
                                                 const float* __restrict__ dinv,
                                                 const float* __restrict__ H,
                                                 float* __restrict__ A, int E) {
  int idx = blockIdx.x * 256 + threadIdx.x;
  int e = idx >> 5;
  if (e >= E) return;
  int l = idx & 31;
  int r = row[e], c = col[e];
  float wv = dinv[r] * dinv[c];
  float4 h4 = *(const float4*)(H + (size_t)r * 128 + l * 4);
  float* dst = A + (size_t)c * 128 + l * 4;
  atomicAdd(dst + 0, h4.x * wv);
  atomicAdd(dst + 1, h4.y * wv);
  atomicAdd(dst + 2, h4.z * wv);
  atomicAdd(dst + 3, h4.w * wv);
}

// ---------------- finalize: A = lrelu(A + H*dinv^2 + b)  (in place) ----------------
__global__ __launch_bounds__(256) void k_finalize(float* __restrict__ A,
                                                  const float* __restrict__ H,
                                                  const float* __restrict__ dinv,
                                                  const float* __restrict__ b, int N) {
  int idx = blockIdx.x * 256 + threadIdx.x;
  int i = idx >> 5;
  if (i >= N) return;
  int l = idx & 31;
  float di = dinv[i];
  float s = di * di;
  float4 a4 = *(float4*)(A + (size_t)i * 128 + l * 4);
  float4 h4 = *(const float4*)(H + (size_t)i * 128 + l * 4);
  float4 b4 = *(const float4*)(b + l * 4);
  a4.x = lrelu(a4.x + h4.x * s + b4.x);
  a4.y = lrelu(a4.y + h4.y * s + b4.y);
  a4.z = lrelu(a4.z + h4.z * s + b4.z);
  a4.w = lrelu(a4.w + h4.w * s + b4.w);
  *(float4*)(A + (size_t)i * 128 + l * 4) = a4;
}

// ---------------- pooling: pooled[g] += H[i], cnt[g] += 1 ----------------
__global__ __launch_bounds__(256) void k_pool(const float* __restrict__ H,
                                              const int* __restrict__ batch,
                                              float* __restrict__ pooled,
                                              float* __restrict__ cnt, int N) {
  int idx = blockIdx.x * 256 + threadIdx.x;
  int i = idx >> 5;
  if (i >= N) return;
  int l = idx & 31;
  int g = batch[i];
  float4 h4 = *(const float4*)(H + (size_t)i * 128 + l * 4);
  float* dst = pooled + (size_t)g * 128 + l * 4;
  atomicAdd(dst + 0, h4.x);
  atomicAdd(dst + 1, h4.y);
  atomicAdd(dst + 2, h4.z);
  atomicAdd(dst + 3, h4.w);
  if (l == 0) atomicAdd(&cnt[g], 1.0f);
}

// ---------------- MLP head: one block per graph, 128 threads ----------------
__global__ __launch_bounds__(128) void k_mlp(const float* __restrict__ pooled,
                                             const float* __restrict__ cnt,
                                             const float* __restrict__ gfeat,
                                             const float* __restrict__ Wg, const float* __restrict__ bg,
                                             const float* __restrict__ Wf, const float* __restrict__ bf,
                                             const float* __restrict__ Wm1, const float* __restrict__ bm1,
                                             const float* __restrict__ Wm2, const float* __restrict__ bm2,
                                             float* __restrict__ out) {
  __shared__ float p[128], q[32], a[256], red[2];
  int g = blockIdx.x, t = threadIdx.x;
  float inv = 1.0f / fmaxf(cnt[g], 1.0f);
  p[t] = pooled[(size_t)g * 128 + t] * inv;
  if (t < 32) q[t] = gfeat[(size_t)g * 32 + t];
  __syncthreads();
  float acc = bg[t];
  for (int m = 0; m < 128; ++m) acc += p[m] * Wg[m * 128 + t];
  float acc2 = bf[t];
  for (int m = 0; m < 32; ++m) acc2 += q[m] * Wf[m * 128 + t];
  a[t] = lrelu(acc);
  a[128 + t] = lrelu(acc2);
  __syncthreads();
  float z = bm1[t];
  for (int k = 0; k < 256; ++k) z += a[k] * Wm1[k * 128 + t];
  z = lrelu(z);
  float v = z * Wm2[t];
#pragma unroll
  for (int off = 32; off; off >>= 1) v += __shfl_down(v, off);
  if ((t & 63) == 0) red[t >> 6] = v;
  __syncthreads();
  if (t == 0) out[g] = red[0] + red[1] + bm2[0];
}

extern "C" void kernel_launch(void* const* d_in, const int* in_sizes, int n_in,
                              void* d_out, int out_size, void* d_ws, size_t ws_size,
                              hipStream_t stream) {
  const float* x     = (const float*)d_in[0];
  const int*   ei    = (const int*)d_in[1];   // [2,E] row-major
  const int*   batch = (const int*)d_in[2];
  const float* gfeat = (const float*)d_in[3];
  const float* W1 = (const float*)d_in[4];
  const float* b1 = (const float*)d_in[5];
  const float* W2 = (const float*)d_in[6];
  const float* b2 = (const float*)d_in[7];
  const float* Wg = (const float*)d_in[8];
  const float* bg = (const float*)d_in[9];
  const float* Wf = (const float*)d_in[10];
  const float* bf = (const float*)d_in[11];
  const float* Wm1 = (const float*)d_in[12];
  const float* bm1 = (const float*)d_in[13];
  const float* Wm2 = (const float*)d_in[14];
  const float* bm2 = (const float*)d_in[15];
  float* out = (float*)d_out;

  const int N = in_sizes[0] / 64;
  const int E = in_sizes[1] / 2;
  const int G = in_sizes[3] / 32;
  const int* row = ei;
  const int* col = ei + E;

  // workspace layout
  char* w = (char*)d_ws;
  size_t offDeg = 0;
  size_t offH   = ((size_t)N * 4 + 511) & ~(size_t)511;
  size_t offAgg = offH + (size_t)N * 128 * 4;
  size_t offPool = offAgg + (size_t)N * 128 * 4;
  size_t offCnt = offPool + (size_t)G * 128 * 4;
  float* deg    = (float*)(w + offDeg);   // becomes dinv
  float* hbuf   = (float*)(w + offH);     // N x 128
  float* agg    = (float*)(w + offAgg);   // N x 128
  float* pooled = (float*)(w + offPool);  // G x 128
  float* cntb   = (float*)(w + offCnt);   // G

  hipMemsetAsync(deg, 0, (size_t)N * 4, stream);
  hipMemsetAsync(agg, 0, (size_t)N * 128 * 4, stream);
  hipMemsetAsync(pooled, 0, ((size_t)G * 128 + G) * 4, stream);

  // degree + dinv
  k_deg<<<(E + 255) / 256, 256, 0, stream>>>(col, deg, E);
  k_dinv<<<(N + 255) / 256, 256, 0, stream>>>(deg, N);

  // layer 1
  k_gemm<64><<<(N + 31) / 32, 256, 0, stream>>>(x, W1, hbuf, N);
  k_scatter<<<(E * 32 + 255) / 256, 256, 0, stream>>>(row, col, deg, hbuf, agg, E);
  k_finalize<<<(N * 32 + 255) / 256, 256, 0, stream>>>(agg, hbuf, deg, b1, N);

  // layer 2 (reuse hbuf for GEMM out, re-zero agg for scatter)
  k_gemm<128><<<(N + 31) / 32, 256, 0, stream>>>(agg, W2, hbuf, N);
  hipMemsetAsync(agg, 0, (size_t)N * 128 * 4, stream);
  k_scatter<<<(E * 32 + 255) / 256, 256, 0, stream>>>(row, col, deg, hbuf, agg, E);
  k_finalize<<<(N * 32 + 255) / 256, 256, 0, stream>>>(agg, hbuf, deg, b2, N);

  // pooling + MLP head
  k_pool<<<(N * 32 + 255) / 256, 256, 0, stream>>>(agg, batch, pooled, cntb, N);
  k_mlp<<<G, 128, 0, stream>>>(pooled, cntb, gfeat, Wg, bg, Wf, bf, Wm1, bm1, Wm2, bm2, out);
}

// Round 2
// 901.435 us; speedup vs baseline: 6.7197x; 6.7197x over previous
//
#include <hip/hip_runtime.h>

__device__ __forceinline__ float lrelu(float v) { return v >= 0.0f ? v : 0.01f * v; }

// ================= CSR build =================
__global__ __launch_bounds__(256) void k_hist(const int* __restrict__ col,
                                              int* __restrict__ degi, int E) {
  int e = blockIdx.x * 256 + threadIdx.x;
  if (e < E) atomicAdd(&degi[col[e]], 1);
}

// inclusive scan of degi per 2048-block -> rowstart[1+i] (pre-offset), block sums
__global__ __launch_bounds__(256) void k_scan1(const int* __restrict__ degi,
                                               int* __restrict__ rowstart,
                                               int* __restrict__ bsums, int N) {
  __shared__ int lds[256];
  int b = blockIdx.x, t = threadIdx.x;
  int base = b * 2048 + t * 8;
  int v[8];
  int run = 0;
#pragma unroll
  for (int j = 0; j < 8; ++j) {
    int x = (base + j < N) ? degi[base + j] : 0;
    run += x;
    v[j] = run;
  }
  lds[t] = run;
  __syncthreads();
  for (int off = 1; off < 256; off <<= 1) {
    int x = (t >= off) ? lds[t - off] : 0;
    __syncthreads();
    lds[t] += x;
    __syncthreads();
  }
  int prev = (t > 0) ? lds[t - 1] : 0;
#pragma unroll
  for (int j = 0; j < 8; ++j)
    if (base + j < N) rowstart[1 + base + j] = v[j] + prev;
  if (t == 255) bsums[b] = lds[255];
}

__global__ void k_scan2(int* __restrict__ bsums, int nblk) {
  if (threadIdx.x == 0) {
    int run = 0;
    for (int i = 0; i < nblk; ++i) { int x = bsums[i]; bsums[i] = run; run += x; }
  }
}

// finalize scan; convert degi -> exclusive start (fill cursor)
__global__ __launch_bounds__(256) void k_scan3(int* __restrict__ degi,
                                               int* __restrict__ rowstart,
                                               const int* __restrict__ bsums, int N) {
  int i = blockIdx.x * 256 + threadIdx.x;
  if (i >= N) return;
  int incl = rowstart[1 + i] + bsums[i >> 11];
  rowstart[1 + i] = incl;
  degi[i] = incl - degi[i];  // exclusive start
  if (i == 0) rowstart[0] = 0;
}

__global__ __launch_bounds__(256) void k_dinv(const int* __restrict__ rowstart,
                                              float* __restrict__ dinv, int N) {
  int i = blockIdx.x * 256 + threadIdx.x;
  if (i < N) dinv[i] = rsqrtf((float)(rowstart[i + 1] - rowstart[i]) + 1.0f);
}

__global__ __launch_bounds__(256) void k_fill(const int* __restrict__ row,
                                              const int* __restrict__ col,
                                              int* __restrict__ cursor,
                                              int* __restrict__ csr_src, int E) {
  int e = blockIdx.x * 256 + threadIdx.x;
  if (e >= E) return;
  int pos = atomicAdd(&cursor[col[e]], 1);
  csr_src[pos] = row[e];
}

// ================= graph boundaries (batch is sorted) =================
__global__ __launch_bounds__(256) void k_bhist(const int* __restrict__ batch,
                                               int* __restrict__ ghist, int N) {
  int i = blockIdx.x * 256 + threadIdx.x;
  if (i < N) atomicAdd(&ghist[batch[i]], 1);
}

__global__ void k_gscan(const int* __restrict__ ghist, int* __restrict__ gstart, int G) {
  if (threadIdx.x == 0) {
    int run = 0;
    for (int g = 0; g < G; ++g) { gstart[g] = run; run += ghist[g]; }
    gstart[G] = run;
  }
}

// ================= GEMM: Y[N,128] = X[N,K] @ W[K,128] =================
template <int K>
__global__ __launch_bounds__(256) void k_gemm(const float* __restrict__ X,
                                              const float* __restrict__ W,
                                              float* __restrict__ Y, int N) {
  __shared__ float Xs[32 * K];
  const int t = threadIdx.x;
  const int row0 = blockIdx.x * 32;
  for (int i = t; i < 32 * K; i += 256) {
    int r = i / K, k = i - r * K;
    int gr = row0 + r;
    Xs[i] = (gr < N) ? X[(size_t)gr * K + k] : 0.0f;
  }
  __syncthreads();
  const int f = t & 127;
  const int rh = t >> 7;
  float acc[16];
#pragma unroll
  for (int r = 0; r < 16; ++r) acc[r] = 0.0f;
  for (int k4 = 0; k4 < K; k4 += 4) {
    float w0 = W[(k4 + 0) * 128 + f];
    float w1 = W[(k4 + 1) * 128 + f];
    float w2 = W[(k4 + 2) * 128 + f];
    float w3 = W[(k4 + 3) * 128 + f];
#pragma unroll
    for (int r = 0; r < 16; ++r) {
      float4 xv = *(const float4*)&Xs[(rh * 16 + r) * K + k4];
      acc[r] += xv.x * w0 + xv.y * w1 + xv.z * w2 + xv.w * w3;
    }
  }
#pragma unroll
  for (int r = 0; r < 16; ++r) {
    int gr = row0 + rh * 16 + r;
    if (gr < N) Y[(size_t)gr * 128 + f] = acc[r];
  }
}

// ================= gather-aggregate + self-loop + bias + LeakyReLU =================
// one 64-lane wave per node, float2 per lane
__global__ __launch_bounds__(256) void k_agg(const int* __restrict__ rowstart,
                                             const int* __restrict__ csr_src,
                                             const float* __restrict__ dinv,
                                             const float* __restrict__ H,
                                             const float* __restrict__ bias,
                                             float* __restrict__ O, int N) {
  int wid = (blockIdx.x * 256 + threadIdx.x) >> 6;
  int lane = threadIdx.x & 63;
  if (wid >= N) return;
  int s = rowstart[wid], e = rowstart[wid + 1];
  float dc = dinv[wid];
  const float2* Hv = (const float2*)H;
  float2 acc = Hv[(size_t)wid * 64 + lane];
  acc.x *= dc * dc;
  acc.y *= dc * dc;  // self loop
  for (int i = s; i < e; ++i) {
    int src = csr_src[i];
    float w = dinv[src] * dc;
    float2 h = Hv[(size_t)src * 64 + lane];
    acc.x += h.x * w;
    acc.y += h.y * w;
  }
  float2 b2 = ((const float2*)bias)[lane];
  acc.x = lrelu(acc.x + b2.x);
  acc.y = lrelu(acc.y + b2.y);
  ((float2*)O)[(size_t)wid * 64 + lane] = acc;
}

// ================= pooling: block per graph, contiguous node range =================
__global__ __launch_bounds__(256) void k_pool(const float* __restrict__ H,
                                              const int* __restrict__ gstart,
                                              float* __restrict__ pooled) {
  __shared__ float lds[256];
  int g = blockIdx.x, t = threadIdx.x;
  int s = gstart[g], e = gstart[g + 1];
  int f = t & 127, half = t >> 7;
  float acc = 0.0f;
  for (int i = s + half; i < e; i += 2) acc += H[(size_t)i * 128 + f];
  lds[t] = acc;
  __syncthreads();
  if (t < 128) {
    float v = lds[t] + lds[t + 128];
    pooled[(size_t)g * 128 + t] = v / fmaxf((float)(e - s), 1.0f);
  }
}

// ================= MLP head =================
__global__ __launch_bounds__(128) void k_mlp(const float* __restrict__ pooled,
                                             const float* __restrict__ gfeat,
                                             const float* __restrict__ Wg, const float* __restrict__ bg,
                                             const float* __restrict__ Wf, const float* __restrict__ bf,
                                             const float* __restrict__ Wm1, const float* __restrict__ bm1,
                                             const float* __restrict__ Wm2, const float* __restrict__ bm2,
                                             float* __restrict__ out) {
  __shared__ float p[128], q[32], a[256], red[2];
  int g = blockIdx.x, t = threadIdx.x;
  p[t] = pooled[(size_t)g * 128 + t];
  if (t < 32) q[t] = gfeat[(size_t)g * 32 + t];
  __syncthreads();
  float acc = bg[t];
  for (int m = 0; m < 128; ++m) acc += p[m] * Wg[m * 128 + t];
  float acc2 = bf[t];
  for (int m = 0; m < 32; ++m) acc2 += q[m] * Wf[m * 128 + t];
  a[t] = lrelu(acc);
  a[128 + t] = lrelu(acc2);
  __syncthreads();
  float z = bm1[t];
  for (int k = 0; k < 256; ++k) z += a[k] * Wm1[k * 128 + t];
  z = lrelu(z);
  float v = z * Wm2[t];
#pragma unroll
  for (int off = 32; off; off >>= 1) v += __shfl_down(v, off);
  if ((t & 63) == 0) red[t >> 6] = v;
  __syncthreads();
  if (t == 0) out[g] = red[0] + red[1] + bm2[0];
}

extern "C" void kernel_launch(void* const* d_in, const int* in_sizes, int n_in,
                              void* d_out, int out_size, void* d_ws, size_t ws_size,
                              hipStream_t stream) {
  const float* x     = (const float*)d_in[0];
  const int*   ei    = (const int*)d_in[1];
  const int*   batch = (const int*)d_in[2];
  const float* gfeat = (const float*)d_in[3];
  const float* W1 = (const float*)d_in[4];
  const float* b1 = (const float*)d_in[5];
  const float* W2 = (const float*)d_in[6];
  const float* b2 = (const float*)d_in[7];
  const float* Wg = (const float*)d_in[8];
  const float* bg = (const float*)d_in[9];
  const float* Wf = (const float*)d_in[10];
  const float* bf = (const float*)d_in[11];
  const float* Wm1 = (const float*)d_in[12];
  const float* bm1 = (const float*)d_in[13];
  const float* Wm2 = (const float*)d_in[14];
  const float* bm2 = (const float*)d_in[15];
  float* out = (float*)d_out;

  const int N = in_sizes[0] / 64;
  const int E = in_sizes[1] / 2;
  const int G = in_sizes[3] / 32;
  const int* row = ei;
  const int* col = ei + E;

  // ---- workspace layout ----
  char* w = (char*)d_ws;
  size_t off = 0;
  auto alloc = [&](size_t bytes) {
    void* p = w + off;
    off = (off + bytes + 255) & ~(size_t)255;
    return p;
  };
  int*   degi     = (int*)alloc((size_t)N * 4);        // hist -> cursor
  int*   rowstart = (int*)alloc((size_t)(N + 1) * 4);
  float* dinv     = (float*)alloc((size_t)N * 4);
  int*   bsums    = (int*)alloc(64 * 4);
  int*   ghist    = (int*)alloc((size_t)G * 4);
  int*   gstart   = (int*)alloc((size_t)(G + 1) * 4);
  float* pooled   = (float*)alloc((size_t)G * 128 * 4);
  int*   csr_src  = (int*)alloc((size_t)E * 4);
  float* hbuf     = (float*)alloc((size_t)N * 128 * 4);
  float* agg      = (float*)alloc((size_t)N * 128 * 4);
  (void)ws_size;

  hipMemsetAsync(degi, 0, (size_t)N * 4, stream);
  hipMemsetAsync(ghist, 0, (size_t)G * 4, stream);

  // CSR build
  const int nblk = (N + 2047) / 2048;
  k_hist<<<(E + 255) / 256, 256, 0, stream>>>(col, degi, E);
  k_scan1<<<nblk, 256, 0, stream>>>(degi, rowstart, bsums, N);
  k_scan2<<<1, 64, 0, stream>>>(bsums, nblk);
  k_scan3<<<(N + 255) / 256, 256, 0, stream>>>(degi, rowstart, bsums, N);
  k_dinv<<<(N + 255) / 256, 256, 0, stream>>>(rowstart, dinv, N);
  k_fill<<<(E + 255) / 256, 256, 0, stream>>>(row, col, degi, csr_src, E);

  // graph boundaries
  k_bhist<<<(N + 255) / 256, 256, 0, stream>>>(batch, ghist, N);
  k_gscan<<<1, 64, 0, stream>>>(ghist, gstart, G);

  // layer 1
  k_gemm<64><<<(N + 31) / 32, 256, 0, stream>>>(x, W1, hbuf, N);
  k_agg<<<(N * 64 + 255) / 256, 256, 0, stream>>>(rowstart, csr_src, dinv, hbuf, b1, agg, N);

  // layer 2
  k_gemm<128><<<(N + 31) / 32, 256, 0, stream>>>(agg, W2, hbuf, N);
  k_agg<<<(N * 64 + 255) / 256, 256, 0, stream>>>(rowstart, csr_src, dinv, hbuf, b2, agg, N);

  // pooling + MLP head
  k_pool<<<G, 256, 0, stream>>>(agg, gstart, pooled);
  k_mlp<<<G, 128, 0, stream>>>(pooled, gfeat, Wg, bg, Wf, bf, Wm1, bm1, Wm2, bm2, out);
}

// Round 3
// 767.255 us; speedup vs baseline: 7.8948x; 1.1749x over previous
//
#include <hip/hip_runtime.h>

__device__ __forceinline__ float lrelu(float v) { return v >= 0.0f ? v : 0.01f * v; }

// ================= CSR build =================
__global__ __launch_bounds__(256) void k_hist(const int* __restrict__ col,
                                              int* __restrict__ degi, int E) {
  int e = blockIdx.x * 256 + threadIdx.x;
  if (e < E) atomicAdd(&degi[col[e]], 1);
}

__global__ __launch_bounds__(256) void k_scan1(const int* __restrict__ degi,
                                               int* __restrict__ rowstart,
                                               int* __restrict__ bsums, int N) {
  __shared__ int lds[256];
  int b = blockIdx.x, t = threadIdx.x;
  int base = b * 2048 + t * 8;
  int v[8];
  int run = 0;
#pragma unroll
  for (int j = 0; j < 8; ++j) {
    int x = (base + j < N) ? degi[base + j] : 0;
    run += x;
    v[j] = run;
  }
  lds[t] = run;
  __syncthreads();
  for (int off = 1; off < 256; off <<= 1) {
    int x = (t >= off) ? lds[t - off] : 0;
    __syncthreads();
    lds[t] += x;
    __syncthreads();
  }
  int prev = (t > 0) ? lds[t - 1] : 0;
#pragma unroll
  for (int j = 0; j < 8; ++j)
    if (base + j < N) rowstart[1 + base + j] = v[j] + prev;
  if (t == 255) bsums[b] = lds[255];
}

__global__ void k_scan2(int* __restrict__ bsums, int nblk) {
  if (threadIdx.x == 0) {
    int run = 0;
    for (int i = 0; i < nblk; ++i) { int x = bsums[i]; bsums[i] = run; run += x; }
  }
}

__global__ __launch_bounds__(256) void k_scan3(int* __restrict__ degi,
                                               int* __restrict__ rowstart,
                                               const int* __restrict__ bsums, int N) {
  int i = blockIdx.x * 256 + threadIdx.x;
  if (i >= N) return;
  int incl = rowstart[1 + i] + bsums[i >> 11];
  rowstart[1 + i] = incl;
  degi[i] = incl - degi[i];  // exclusive start (fill cursor)
  if (i == 0) rowstart[0] = 0;
}

__global__ __launch_bounds__(256) void k_dinv(const int* __restrict__ rowstart,
                                              float* __restrict__ dinv, int N) {
  int i = blockIdx.x * 256 + threadIdx.x;
  if (i < N) dinv[i] = rsqrtf((float)(rowstart[i + 1] - rowstart[i]) + 1.0f);
}

// fill CSR src + per-edge weight dinv[r]*dinv[c]
__global__ __launch_bounds__(256) void k_fill(const int* __restrict__ row,
                                              const int* __restrict__ col,
                                              const float* __restrict__ dinv,
                                              int* __restrict__ cursor,
                                              int* __restrict__ csr_src,
                                              float* __restrict__ csr_w, int E) {
  int e = blockIdx.x * 256 + threadIdx.x;
  if (e >= E) return;
  int r = row[e], c = col[e];
  int pos = atomicAdd(&cursor[c], 1);
  csr_src[pos] = r;
  csr_w[pos] = dinv[r] * dinv[c];
}

// ================= graph boundaries (batch sorted) =================
__global__ __launch_bounds__(256) void k_bhist(const int* __restrict__ batch,
                                               int* __restrict__ ghist, int N) {
  int i = blockIdx.x * 256 + threadIdx.x;
  if (i < N) atomicAdd(&ghist[batch[i]], 1);
}

__global__ void k_gscan(const int* __restrict__ ghist, int* __restrict__ gstart, int G) {
  if (threadIdx.x == 0) {
    int run = 0;
    for (int g = 0; g < G; ++g) { gstart[g] = run; run += ghist[g]; }
    gstart[G] = run;
  }
}

// ================= gather-aggregate (linear): O = Â·X =================
// one 64-lane wave per node; FPL floats per lane (1 for 64-dim, 2 for 128-dim)
__global__ __launch_bounds__(256) void k_agg64(const int* __restrict__ rowstart,
                                               const int* __restrict__ csr_src,
                                               const float* __restrict__ csr_w,
                                               const float* __restrict__ dinv,
                                               const float* __restrict__ X,
                                               float* __restrict__ O, int N) {
  int wid = (blockIdx.x * 256 + threadIdx.x) >> 6;
  int lane = threadIdx.x & 63;
  if (wid >= N) return;
  int s = rowstart[wid], e = rowstart[wid + 1];
  float dc = dinv[wid];
  float acc = X[(size_t)wid * 64 + lane] * dc * dc;  // self loop
#pragma unroll 2
  for (int i = s; i < e; ++i) {
    int src = csr_src[i];
    float w = csr_w[i];
    acc += X[(size_t)src * 64 + lane] * w;
  }
  O[(size_t)wid * 64 + lane] = acc;
}

__global__ __launch_bounds__(256) void k_agg128(const int* __restrict__ rowstart,
                                                const int* __restrict__ csr_src,
                                                const float* __restrict__ csr_w,
                                                const float* __restrict__ dinv,
                                                const float* __restrict__ H,
                                                float* __restrict__ O, int N) {
  int wid = (blockIdx.x * 256 + threadIdx.x) >> 6;
  int lane = threadIdx.x & 63;
  if (wid >= N) return;
  int s = rowstart[wid], e = rowstart[wid + 1];
  float dc = dinv[wid];
  const float2* Hv = (const float2*)H;
  float2 acc = Hv[(size_t)wid * 64 + lane];
  acc.x *= dc * dc;
  acc.y *= dc * dc;
#pragma unroll 2
  for (int i = s; i < e; ++i) {
    int src = csr_src[i];
    float w = csr_w[i];
    float2 h = Hv[(size_t)src * 64 + lane];
    acc.x += h.x * w;
    acc.y += h.y * w;
  }
  ((float2*)O)[(size_t)wid * 64 + lane] = acc;
}

// ================= GEMM + bias + LeakyReLU: Y[N,128] = act(X[N,K] @ W + b) =================
// in-place safe (Y may alias X): block stages its own rows in LDS before writing.
template <int K>
__global__ __launch_bounds__(256) void k_gemm_act(const float* __restrict__ X,
                                                  const float* __restrict__ W,
                                                  const float* __restrict__ bias,
                                                  float* __restrict__ Y, int N) {
  __shared__ float Xs[32 * K];
  const int t = threadIdx.x;
  const int row0 = blockIdx.x * 32;
  for (int i = t; i < 32 * K; i += 256) {
    int r = i / K, k = i - r * K;
    int gr = row0 + r;
    Xs[i] = (gr < N) ? X[(size_t)gr * K + k] : 0.0f;
  }
  __syncthreads();
  const int f = t & 127;
  const int rh = t >> 7;
  float acc[16];
#pragma unroll
  for (int r = 0; r < 16; ++r) acc[r] = 0.0f;
  for (int k4 = 0; k4 < K; k4 += 4) {
    float w0 = W[(k4 + 0) * 128 + f];
    float w1 = W[(k4 + 1) * 128 + f];
    float w2 = W[(k4 + 2) * 128 + f];
    float w3 = W[(k4 + 3) * 128 + f];
#pragma unroll
    for (int r = 0; r < 16; ++r) {
      float4 xv = *(const float4*)&Xs[(rh * 16 + r) * K + k4];
      acc[r] += xv.x * w0 + xv.y * w1 + xv.z * w2 + xv.w * w3;
    }
  }
  float b = bias[f];
#pragma unroll
  for (int r = 0; r < 16; ++r) {
    int gr = row0 + rh * 16 + r;
    if (gr < N) Y[(size_t)gr * 128 + f] = lrelu(acc[r] + b);
  }
}

// ================= pooling: block per graph =================
__global__ __launch_bounds__(256) void k_pool(const float* __restrict__ H,
                                              const int* __restrict__ gstart,
                                              float* __restrict__ pooled) {
  __shared__ float lds[256];
  int g = blockIdx.x, t = threadIdx.x;
  int s = gstart[g], e = gstart[g + 1];
  int f = t & 127, half = t >> 7;
  float acc = 0.0f;
  for (int i = s + half; i < e; i += 2) acc += H[(size_t)i * 128 + f];
  lds[t] = acc;
  __syncthreads();
  if (t < 128) {
    float v = lds[t] + lds[t + 128];
    pooled[(size_t)g * 128 + t] = v / fmaxf((float)(e - s), 1.0f);
  }
}

// ================= MLP head =================
__global__ __launch_bounds__(128) void k_mlp(const float* __restrict__ pooled,
                                             const float* __restrict__ gfeat,
                                             const float* __restrict__ Wg, const float* __restrict__ bg,
                                             const float* __restrict__ Wf, const float* __restrict__ bf,
                                             const float* __restrict__ Wm1, const float* __restrict__ bm1,
                                             const float* __restrict__ Wm2, const float* __restrict__ bm2,
                                             float* __restrict__ out) {
  __shared__ float p[128], q[32], a[256], red[2];
  int g = blockIdx.x, t = threadIdx.x;
  p[t] = pooled[(size_t)g * 128 + t];
  if (t < 32) q[t] = gfeat[(size_t)g * 32 + t];
  __syncthreads();
  float acc = bg[t];
  for (int m = 0; m < 128; ++m) acc += p[m] * Wg[m * 128 + t];
  float acc2 = bf[t];
  for (int m = 0; m < 32; ++m) acc2 += q[m] * Wf[m * 128 + t];
  a[t] = lrelu(acc);
  a[128 + t] = lrelu(acc2);
  __syncthreads();
  float z = bm1[t];
  for (int k = 0; k < 256; ++k) z += a[k] * Wm1[k * 128 + t];
  z = lrelu(z);
  float v = z * Wm2[t];
#pragma unroll
  for (int off = 32; off; off >>= 1) v += __shfl_down(v, off);
  if ((t & 63) == 0) red[t >> 6] = v;
  __syncthreads();
  if (t == 0) out[g] = red[0] + red[1] + bm2[0];
}

extern "C" void kernel_launch(void* const* d_in, const int* in_sizes, int n_in,
                              void* d_out, int out_size, void* d_ws, size_t ws_size,
                              hipStream_t stream) {
  const float* x     = (const float*)d_in[0];
  const int*   ei    = (const int*)d_in[1];
  const int*   batch = (const int*)d_in[2];
  const float* gfeat = (const float*)d_in[3];
  const float* W1 = (const float*)d_in[4];
  const float* b1 = (const float*)d_in[5];
  const float* W2 = (const float*)d_in[6];
  const float* b2 = (const float*)d_in[7];
  const float* Wg = (const float*)d_in[8];
  const float* bg = (const float*)d_in[9];
  const float* Wf = (const float*)d_in[10];
  const float* bf = (const float*)d_in[11];
  const float* Wm1 = (const float*)d_in[12];
  const float* bm1 = (const float*)d_in[13];
  const float* Wm2 = (const float*)d_in[14];
  const float* bm2 = (const float*)d_in[15];
  float* out = (float*)d_out;

  const int N = in_sizes[0] / 64;
  const int E = in_sizes[1] / 2;
  const int G = in_sizes[3] / 32;
  const int* row = ei;
  const int* col = ei + E;

  // ---- workspace layout ----
  char* w = (char*)d_ws;
  size_t off = 0;
  auto alloc = [&](size_t bytes) {
    void* p = w + off;
    off = (off + bytes + 255) & ~(size_t)255;
    return p;
  };
  int*   degi     = (int*)alloc((size_t)N * 4);
  int*   rowstart = (int*)alloc((size_t)(N + 1) * 4);
  float* dinv     = (float*)alloc((size_t)N * 4);
  int*   bsums    = (int*)alloc(64 * 4);
  int*   ghist    = (int*)alloc((size_t)G * 4);
  int*   gstart   = (int*)alloc((size_t)(G + 1) * 4);
  float* pooled   = (float*)alloc((size_t)G * 128 * 4);
  int*   csr_src  = (int*)alloc((size_t)E * 4);
  float* csr_w    = (float*)alloc((size_t)E * 4);
  float* P1       = (float*)alloc((size_t)N * 128 * 4);  // aggX (N*64) then h2 (N*128)
  float* P2       = (float*)alloc((size_t)N * 128 * 4);  // h1
  (void)ws_size;

  hipMemsetAsync(degi, 0, (size_t)N * 4, stream);
  hipMemsetAsync(ghist, 0, (size_t)G * 4, stream);

  // CSR build
  const int nblk = (N + 2047) / 2048;
  k_hist<<<(E + 255) / 256, 256, 0, stream>>>(col, degi, E);
  k_scan1<<<nblk, 256, 0, stream>>>(degi, rowstart, bsums, N);
  k_scan2<<<1, 64, 0, stream>>>(bsums, nblk);
  k_scan3<<<(N + 255) / 256, 256, 0, stream>>>(degi, rowstart, bsums, N);
  k_dinv<<<(N + 255) / 256, 256, 0, stream>>>(rowstart, dinv, N);
  k_fill<<<(E + 255) / 256, 256, 0, stream>>>(row, col, dinv, degi, csr_src, csr_w, E);

  // graph boundaries
  k_bhist<<<(N + 255) / 256, 256, 0, stream>>>(batch, ghist, N);
  k_gscan<<<1, 64, 0, stream>>>(ghist, gstart, G);

  const int aggGrid = (N * 64 + 255) / 256;

  // layer 1: aggregate in 64-dim input space, then GEMM(+bias+lrelu)
  k_agg64<<<aggGrid, 256, 0, stream>>>(rowstart, csr_src, csr_w, dinv, x, P1, N);
  k_gemm_act<64><<<(N + 31) / 32, 256, 0, stream>>>(P1, W1, b1, P2, N);

  // layer 2: aggregate h1, then GEMM(+bias+lrelu) in-place
  k_agg128<<<aggGrid, 256, 0, stream>>>(rowstart, csr_src, csr_w, dinv, P2, P1, N);
  k_gemm_act<128><<<(N + 31) / 32, 256, 0, stream>>>(P1, W2, b2, P1, N);

  // pooling + MLP head
  k_pool<<<G, 256, 0, stream>>>(P1, gstart, pooled);
  k_mlp<<<G, 128, 0, stream>>>(pooled, gfeat, Wg, bg, Wf, bf, Wm1, bm1, Wm2, bm2, out);
}

// Round 4
// 600.148 us; speedup vs baseline: 10.0931x; 1.2784x over previous
//
#include <hip/hip_runtime.h>

__device__ __forceinline__ float lrelu(float v) { return v >= 0.0f ? v : 0.01f * v; }

// ================= CSR build =================
__global__ __launch_bounds__(256) void k_hist(const int* __restrict__ col,
                                              int* __restrict__ degi, int E) {
  int e = blockIdx.x * 256 + threadIdx.x;
  if (e < E) atomicAdd(&degi[col[e]], 1);
}

__global__ __launch_bounds__(256) void k_scan1(const int* __restrict__ degi,
                                               int* __restrict__ rowstart,
                                               int* __restrict__ bsums, int N) {
  __shared__ int lds[256];
  int b = blockIdx.x, t = threadIdx.x;
  int base = b * 2048 + t * 8;
  int v[8];
  int run = 0;
#pragma unroll
  for (int j = 0; j < 8; ++j) {
    int x = (base + j < N) ? degi[base + j] : 0;
    run += x;
    v[j] = run;
  }
  lds[t] = run;
  __syncthreads();
  for (int off = 1; off < 256; off <<= 1) {
    int x = (t >= off) ? lds[t - off] : 0;
    __syncthreads();
    lds[t] += x;
    __syncthreads();
  }
  int prev = (t > 0) ? lds[t - 1] : 0;
#pragma unroll
  for (int j = 0; j < 8; ++j)
    if (base + j < N) rowstart[1 + base + j] = v[j] + prev;
  if (t == 255) bsums[b] = lds[255];
}

// parallel scan of block sums (nblk <= 64), single block of 64 threads
__global__ void k_scan2(int* __restrict__ bsums, int nblk) {
  __shared__ int lds[64];
  int t = threadIdx.x;
  int v = (t < nblk) ? bsums[t] : 0;
  lds[t] = v;
  __syncthreads();
  for (int off = 1; off < 64; off <<= 1) {
    int x = (t >= off) ? lds[t - off] : 0;
    __syncthreads();
    lds[t] += x;
    __syncthreads();
  }
  if (t < nblk) bsums[t] = (t > 0) ? lds[t - 1] : 0;  // exclusive
}

__global__ __launch_bounds__(256) void k_scan3(int* __restrict__ degi,
                                               int* __restrict__ rowstart,
                                               const int* __restrict__ bsums, int N) {
  int i = blockIdx.x * 256 + threadIdx.x;
  if (i >= N) return;
  int incl = rowstart[1 + i] + bsums[i >> 11];
  rowstart[1 + i] = incl;
  degi[i] = incl - degi[i];  // exclusive start (fill cursor)
  if (i == 0) rowstart[0] = 0;
}

__global__ __launch_bounds__(256) void k_dinv(const int* __restrict__ rowstart,
                                              float* __restrict__ dinv, int N) {
  int i = blockIdx.x * 256 + threadIdx.x;
  if (i < N) dinv[i] = rsqrtf((float)(rowstart[i + 1] - rowstart[i]) + 1.0f);
}

// fill CSR src + per-edge weight dinv[r]*dinv[c]
__global__ __launch_bounds__(256) void k_fill(const int* __restrict__ row,
                                              const int* __restrict__ col,
                                              const float* __restrict__ dinv,
                                              int* __restrict__ cursor,
                                              int* __restrict__ csr_src,
                                              float* __restrict__ csr_w, int E) {
  int e = blockIdx.x * 256 + threadIdx.x;
  if (e >= E) return;
  int r = row[e], c = col[e];
  int pos = atomicAdd(&cursor[c], 1);
  csr_src[pos] = r;
  csr_w[pos] = dinv[r] * dinv[c];
}

// ================= graph boundaries: batch sorted -> boundary detection =================
__global__ __launch_bounds__(256) void k_gbound(const int* __restrict__ batch,
                                                int* __restrict__ gstart, int N, int G) {
  int i = blockIdx.x * 256 + threadIdx.x;
  if (i >= N) return;
  int b = batch[i];
  int prev = (i == 0) ? -1 : batch[i - 1];
  for (int g = prev + 1; g <= b; ++g) gstart[g] = i;  // usually 0 or 1 iterations
  if (i == N - 1)
    for (int g = b + 1; g <= G; ++g) gstart[g] = N;
}

// ================= gather-aggregate (linear): O = Â·X =================
__global__ __launch_bounds__(256) void k_agg64(const int* __restrict__ rowstart,
                                               const int* __restrict__ csr_src,
                                               const float* __restrict__ csr_w,
                                               const float* __restrict__ dinv,
                                               const float* __restrict__ X,
                                               float* __restrict__ O, int N) {
  int wid = (blockIdx.x * 256 + threadIdx.x) >> 6;
  int lane = threadIdx.x & 63;
  if (wid >= N) return;
  int s = rowstart[wid], e = rowstart[wid + 1];
  float dc = dinv[wid];
  float acc = X[(size_t)wid * 64 + lane] * dc * dc;  // self loop
#pragma unroll 2
  for (int i = s; i < e; ++i) {
    int src = csr_src[i];
    float w = csr_w[i];
    acc += X[(size_t)src * 64 + lane] * w;
  }
  O[(size_t)wid * 64 + lane] = acc;
}

__global__ __launch_bounds__(256) void k_agg128(const int* __restrict__ rowstart,
                                                const int* __restrict__ csr_src,
                                                const float* __restrict__ csr_w,
                                                const float* __restrict__ dinv,
                                                const float* __restrict__ H,
                                                float* __restrict__ O, int N) {
  int wid = (blockIdx.x * 256 + threadIdx.x) >> 6;
  int lane = threadIdx.x & 63;
  if (wid >= N) return;
  int s = rowstart[wid], e = rowstart[wid + 1];
  float dc = dinv[wid];
  const float2* Hv = (const float2*)H;
  float2 acc = Hv[(size_t)wid * 64 + lane];
  acc.x *= dc * dc;
  acc.y *= dc * dc;
#pragma unroll 2
  for (int i = s; i < e; ++i) {
    int src = csr_src[i];
    float w = csr_w[i];
    float2 h = Hv[(size_t)src * 64 + lane];
    acc.x += h.x * w;
    acc.y += h.y * w;
  }
  ((float2*)O)[(size_t)wid * 64 + lane] = acc;
}

// ================= GEMM + bias + LeakyReLU (in-place safe) =================
template <int K>
__global__ __launch_bounds__(256) void k_gemm_act(const float* __restrict__ X,
                                                  const float* __restrict__ W,
                                                  const float* __restrict__ bias,
                                                  float* __restrict__ Y, int N) {
  __shared__ float Xs[32 * K];
  const int t = threadIdx.x;
  const int row0 = blockIdx.x * 32;
  for (int i = t; i < 32 * K; i += 256) {
    int r = i / K, k = i - r * K;
    int gr = row0 + r;
    Xs[i] = (gr < N) ? X[(size_t)gr * K + k] : 0.0f;
  }
  __syncthreads();
  const int f = t & 127;
  const int rh = t >> 7;
  float acc[16];
#pragma unroll
  for (int r = 0; r < 16; ++r) acc[r] = 0.0f;
  for (int k4 = 0; k4 < K; k4 += 4) {
    float w0 = W[(k4 + 0) * 128 + f];
    float w1 = W[(k4 + 1) * 128 + f];
    float w2 = W[(k4 + 2) * 128 + f];
    float w3 = W[(k4 + 3) * 128 + f];
#pragma unroll
    for (int r = 0; r < 16; ++r) {
      float4 xv = *(const float4*)&Xs[(rh * 16 + r) * K + k4];
      acc[r] += xv.x * w0 + xv.y * w1 + xv.z * w2 + xv.w * w3;
    }
  }
  float b = bias[f];
#pragma unroll
  for (int r = 0; r < 16; ++r) {
    int gr = row0 + rh * 16 + r;
    if (gr < N) Y[(size_t)gr * 128 + f] = lrelu(acc[r] + b);
  }
}

// ================= pooling: block per graph =================
__global__ __launch_bounds__(256) void k_pool(const float* __restrict__ H,
                                              const int* __restrict__ gstart,
                                              float* __restrict__ pooled) {
  __shared__ float lds[256];
  int g = blockIdx.x, t = threadIdx.x;
  int s = gstart[g], e = gstart[g + 1];
  int f = t & 127, half = t >> 7;
  float acc = 0.0f;
  for (int i = s + half; i < e; i += 2) acc += H[(size_t)i * 128 + f];
  lds[t] = acc;
  __syncthreads();
  if (t < 128) {
    float v = lds[t] + lds[t + 128];
    pooled[(size_t)g * 128 + t] = v / fmaxf((float)(e - s), 1.0f);
  }
}

// ================= MLP head =================
__global__ __launch_bounds__(128) void k_mlp(const float* __restrict__ pooled,
                                             const float* __restrict__ gfeat,
                                             const float* __restrict__ Wg, const float* __restrict__ bg,
                                             const float* __restrict__ Wf, const float* __restrict__ bf,
                                             const float* __restrict__ Wm1, const float* __restrict__ bm1,
                                             const float* __restrict__ Wm2, const float* __restrict__ bm2,
                                             float* __restrict__ out) {
  __shared__ float p[128], q[32], a[256], red[2];
  int g = blockIdx.x, t = threadIdx.x;
  p[t] = pooled[(size_t)g * 128 + t];
  if (t < 32) q[t] = gfeat[(size_t)g * 32 + t];
  __syncthreads();
  float acc = bg[t];
  for (int m = 0; m < 128; ++m) acc += p[m] * Wg[m * 128 + t];
  float acc2 = bf[t];
  for (int m = 0; m < 32; ++m) acc2 += q[m] * Wf[m * 128 + t];
  a[t] = lrelu(acc);
  a[128 + t] = lrelu(acc2);
  __syncthreads();
  float z = bm1[t];
  for (int k = 0; k < 256; ++k) z += a[k] * Wm1[k * 128 + t];
  z = lrelu(z);
  float v = z * Wm2[t];
#pragma unroll
  for (int off = 32; off; off >>= 1) v += __shfl_down(v, off);
  if ((t & 63) == 0) red[t >> 6] = v;
  __syncthreads();
  if (t == 0) out[g] = red[0] + red[1] + bm2[0];
}

extern "C" void kernel_launch(void* const* d_in, const int* in_sizes, int n_in,
                              void* d_out, int out_size, void* d_ws, size_t ws_size,
                              hipStream_t stream) {
  const float* x     = (const float*)d_in[0];
  const int*   ei    = (const int*)d_in[1];
  const int*   batch = (const int*)d_in[2];
  const float* gfeat = (const float*)d_in[3];
  const float* W1 = (const float*)d_in[4];
  const float* b1 = (const float*)d_in[5];
  const float* W2 = (const float*)d_in[6];
  const float* b2 = (const float*)d_in[7];
  const float* Wg = (const float*)d_in[8];
  const float* bg = (const float*)d_in[9];
  const float* Wf = (const float*)d_in[10];
  const float* bf = (const float*)d_in[11];
  const float* Wm1 = (const float*)d_in[12];
  const float* bm1 = (const float*)d_in[13];
  const float* Wm2 = (const float*)d_in[14];
  const float* bm2 = (const float*)d_in[15];
  float* out = (float*)d_out;

  const int N = in_sizes[0] / 64;
  const int E = in_sizes[1] / 2;
  const int G = in_sizes[3] / 32;
  const int* row = ei;
  const int* col = ei + E;

  // ---- workspace layout ----
  char* w = (char*)d_ws;
  size_t off = 0;
  auto alloc = [&](size_t bytes) {
    void* p = w + off;
    off = (off + bytes + 255) & ~(size_t)255;
    return p;
  };
  int*   degi     = (int*)alloc((size_t)N * 4);
  int*   rowstart = (int*)alloc((size_t)(N + 1) * 4);
  float* dinv     = (float*)alloc((size_t)N * 4);
  int*   bsums    = (int*)alloc(64 * 4);
  int*   gstart   = (int*)alloc((size_t)(G + 1) * 4);
  float* pooled   = (float*)alloc((size_t)G * 128 * 4);
  int*   csr_src  = (int*)alloc((size_t)E * 4);
  float* csr_w    = (float*)alloc((size_t)E * 4);
  float* P1       = (float*)alloc((size_t)N * 128 * 4);
  float* P2       = (float*)alloc((size_t)N * 128 * 4);
  (void)ws_size;

  hipMemsetAsync(degi, 0, (size_t)N * 4, stream);

  // CSR build
  const int nblk = (N + 2047) / 2048;
  k_hist<<<(E + 255) / 256, 256, 0, stream>>>(col, degi, E);
  k_scan1<<<nblk, 256, 0, stream>>>(degi, rowstart, bsums, N);
  k_scan2<<<1, 64, 0, stream>>>(bsums, nblk);
  k_scan3<<<(N + 255) / 256, 256, 0, stream>>>(degi, rowstart, bsums, N);
  k_dinv<<<(N + 255) / 256, 256, 0, stream>>>(rowstart, dinv, N);
  k_fill<<<(E + 255) / 256, 256, 0, stream>>>(row, col, dinv, degi, csr_src, csr_w, E);

  // graph boundaries (no atomics: batch is sorted)
  k_gbound<<<(N + 255) / 256, 256, 0, stream>>>(batch, gstart, N, G);

  const int aggGrid = (N * 64 + 255) / 256;

  // layer 1: aggregate in 64-dim input space, then GEMM(+bias+lrelu)
  k_agg64<<<aggGrid, 256, 0, stream>>>(rowstart, csr_src, csr_w, dinv, x, P1, N);
  k_gemm_act<64><<<(N + 31) / 32, 256, 0, stream>>>(P1, W1, b1, P2, N);

  // layer 2: aggregate h1, then GEMM(+bias+lrelu) in-place
  k_agg128<<<aggGrid, 256, 0, stream>>>(rowstart, csr_src, csr_w, dinv, P2, P1, N);
  k_gemm_act<128><<<(N + 31) / 32, 256, 0, stream>>>(P1, W2, b2, P1, N);

  // pooling + MLP head
  k_pool<<<G, 256, 0, stream>>>(P1, gstart, pooled);
  k_mlp<<<G, 128, 0, stream>>>(pooled, gfeat, Wg, bg, Wf, bf, Wm1, bm1, Wm2, bm2, out);
}

// Round 5
// 486.583 us; speedup vs baseline: 12.4488x; 1.2334x over previous
//
#include <hip/hip_runtime.h>
#include <hip/hip_fp16.h>

__device__ __forceinline__ float lrelu(float v) { return v >= 0.0f ? v : 0.01f * v; }

// ================= CSR build =================
__global__ __launch_bounds__(256) void k_hist(const int* __restrict__ col,
                                              int* __restrict__ degi, int E) {
  int e = blockIdx.x * 256 + threadIdx.x;
  if (e < E) atomicAdd(&degi[col[e]], 1);
}

__global__ __launch_bounds__(256) void k_scan1(const int* __restrict__ degi,
                                               int* __restrict__ rowstart,
                                               int* __restrict__ bsums, int N) {
  __shared__ int lds[256];
  int b = blockIdx.x, t = threadIdx.x;
  int base = b * 2048 + t * 8;
  int v[8];
  int run = 0;
#pragma unroll
  for (int j = 0; j < 8; ++j) {
    int x = (base + j < N) ? degi[base + j] : 0;
    run += x;
    v[j] = run;
  }
  lds[t] = run;
  __syncthreads();
  for (int off = 1; off < 256; off <<= 1) {
    int x = (t >= off) ? lds[t - off] : 0;
    __syncthreads();
    lds[t] += x;
    __syncthreads();
  }
  int prev = (t > 0) ? lds[t - 1] : 0;
#pragma unroll
  for (int j = 0; j < 8; ++j)
    if (base + j < N) rowstart[1 + base + j] = v[j] + prev;
  if (t == 255) bsums[b] = lds[255];
}

__global__ void k_scan2(int* __restrict__ bsums, int nblk) {
  __shared__ int lds[64];
  int t = threadIdx.x;
  int v = (t < nblk) ? bsums[t] : 0;
  lds[t] = v;
  __syncthreads();
  for (int off = 1; off < 64; off <<= 1) {
    int x = (t >= off) ? lds[t - off] : 0;
    __syncthreads();
    lds[t] += x;
    __syncthreads();
  }
  if (t < nblk) bsums[t] = (t > 0) ? lds[t - 1] : 0;  // exclusive
}

// finalize scan; degi -> exclusive start (fill cursor); also dinv = rsqrt(deg+1)
__global__ __launch_bounds__(256) void k_scan3(int* __restrict__ degi,
                                               int* __restrict__ rowstart,
                                               const int* __restrict__ bsums,
                                               float* __restrict__ dinv, int N) {
  int i = blockIdx.x * 256 + threadIdx.x;
  if (i >= N) return;
  int cnt = degi[i];
  int incl = rowstart[1 + i] + bsums[i >> 11];
  rowstart[1 + i] = incl;
  degi[i] = incl - cnt;  // exclusive start
  dinv[i] = rsqrtf((float)cnt + 1.0f);
  if (i == 0) rowstart[0] = 0;
}

// fill CSR src + per-edge weight dinv[r]*dinv[c]
__global__ __launch_bounds__(256) void k_fill(const int* __restrict__ row,
                                              const int* __restrict__ col,
                                              const float* __restrict__ dinv,
                                              int* __restrict__ cursor,
                                              int* __restrict__ csr_src,
                                              float* __restrict__ csr_w, int E) {
  int e = blockIdx.x * 256 + threadIdx.x;
  if (e >= E) return;
  int r = row[e], c = col[e];
  int pos = atomicAdd(&cursor[c], 1);
  csr_src[pos] = r;
  csr_w[pos] = dinv[r] * dinv[c];
}

// ================= graph boundaries (batch sorted) =================
__global__ __launch_bounds__(256) void k_gbound(const int* __restrict__ batch,
                                                int* __restrict__ gstart, int N, int G) {
  int i = blockIdx.x * 256 + threadIdx.x;
  if (i >= N) return;
  int b = batch[i];
  int prev = (i == 0) ? -1 : batch[i - 1];
  for (int g = prev + 1; g <= b; ++g) gstart[g] = i;
  if (i == N - 1)
    for (int g = b + 1; g <= G; ++g) gstart[g] = N;
}

// ================= x fp32 -> fp16 =================
__global__ __launch_bounds__(256) void k_cvt_x(const float* __restrict__ X,
                                               __half* __restrict__ Xh, size_t total4) {
  size_t i = (size_t)(blockIdx.x * 256 + threadIdx.x);
  if (i >= total4) return;
  float4 v = *(const float4*)&X[i * 4];
  __half2* dst = (__half2*)&Xh[i * 4];
  dst[0] = __floats2half2_rn(v.x, v.y);
  dst[1] = __floats2half2_rn(v.z, v.w);
}

// ================= gather-aggregate (linear, fp16 sources) =================
// one 64-lane wave per node; 64-dim: 1 half/lane; self term from fp32 x
__global__ __launch_bounds__(256) void k_agg64h(const int* __restrict__ rowstart,
                                                const int* __restrict__ csr_src,
                                                const float* __restrict__ csr_w,
                                                const float* __restrict__ dinv,
                                                const float* __restrict__ X,
                                                const __half* __restrict__ Xh,
                                                float* __restrict__ O, int N) {
  int wid = (blockIdx.x * 256 + threadIdx.x) >> 6;
  int lane = threadIdx.x & 63;
  if (wid >= N) return;
  int s = rowstart[wid], e = rowstart[wid + 1];
  float dc = dinv[wid];
  float acc = X[(size_t)wid * 64 + lane] * dc * dc;  // self loop (fp32, free precision)
#pragma unroll 4
  for (int i = s; i < e; ++i) {
    int src = csr_src[i];
    float w = csr_w[i];
    acc += __half2float(Xh[(size_t)src * 64 + lane]) * w;
  }
  O[(size_t)wid * 64 + lane] = acc;
}

// 128-dim: half2 per lane
__global__ __launch_bounds__(256) void k_agg128h(const int* __restrict__ rowstart,
                                                 const int* __restrict__ csr_src,
                                                 const float* __restrict__ csr_w,
                                                 const float* __restrict__ dinv,
                                                 const __half* __restrict__ H,
                                                 float* __restrict__ O, int N) {
  int wid = (blockIdx.x * 256 + threadIdx.x) >> 6;
  int lane = threadIdx.x & 63;
  if (wid >= N) return;
  int s = rowstart[wid], e = rowstart[wid + 1];
  float dc = dinv[wid];
  const __half2* Hv = (const __half2*)H;
  float2 hs = __half22float2(Hv[(size_t)wid * 64 + lane]);
  float2 acc;
  acc.x = hs.x * dc * dc;
  acc.y = hs.y * dc * dc;
#pragma unroll 4
  for (int i = s; i < e; ++i) {
    int src = csr_src[i];
    float w = csr_w[i];
    float2 h = __half22float2(Hv[(size_t)src * 64 + lane]);
    acc.x += h.x * w;
    acc.y += h.y * w;
  }
  ((float2*)O)[(size_t)wid * 64 + lane] = acc;
}

// ================= GEMM + bias + LeakyReLU, register-tiled =================
// tile 32 rows x 128 cols, 256 threads, 4x4 per thread.
// X^T staged in LDS with XOR swizzle (conflict-free b128 reads), W streamed b128 from L1/L2.
// In-place safe (Y may alias X): block stages its own rows before writing.
template <int K, bool HALF_OUT>
__global__ __launch_bounds__(256) void k_gemm_rt(const float* __restrict__ X,
                                                 const float* __restrict__ W,
                                                 const float* __restrict__ bias,
                                                 void* __restrict__ Yv, int N) {
  __shared__ float Xs[K * 32];
  const int t = threadIdx.x;
  const int row0 = blockIdx.x * 32;
  for (int i = t; i < 32 * K; i += 256) {
    int r = i / K, k = i % K;
    int gr = row0 + r;
    float v = (gr < N) ? X[(size_t)gr * K + k] : 0.0f;
    Xs[(k << 5) + ((((r >> 2) ^ (k & 7))) << 2) + (r & 3)] = v;
  }
  __syncthreads();
  const int tcol = t & 31, trow = t >> 5;
  const int c0 = tcol << 2;
  float a0x = 0, a0y = 0, a0z = 0, a0w = 0;
  float a1x = 0, a1y = 0, a1z = 0, a1w = 0;
  float a2x = 0, a2y = 0, a2z = 0, a2w = 0;
  float a3x = 0, a3y = 0, a3z = 0, a3w = 0;
#pragma unroll 4
  for (int k = 0; k < K; ++k) {
    float4 xv = *(const float4*)&Xs[(k << 5) + ((trow ^ (k & 7)) << 2)];
    float4 wv = *(const float4*)&W[k * 128 + c0];
    a0x += xv.x * wv.x; a0y += xv.x * wv.y; a0z += xv.x * wv.z; a0w += xv.x * wv.w;
    a1x += xv.y * wv.x; a1y += xv.y * wv.y; a1z += xv.y * wv.z; a1w += xv.y * wv.w;
    a2x += xv.z * wv.x; a2y += xv.z * wv.y; a2z += xv.z * wv.z; a2w += xv.z * wv.w;
    a3x += xv.w * wv.x; a3y += xv.w * wv.y; a3z += xv.w * wv.z; a3w += xv.w * wv.w;
  }
  float4 bv = *(const float4*)&bias[c0];
  float rx[4][4] = {{a0x, a0y, a0z, a0w},
                    {a1x, a1y, a1z, a1w},
                    {a2x, a2y, a2z, a2w},
                    {a3x, a3y, a3z, a3w}};
#pragma unroll
  for (int i = 0; i < 4; ++i) {
    int gr = row0 + (trow << 2) + i;
    if (gr >= N) break;
    float y0 = lrelu(rx[i][0] + bv.x);
    float y1 = lrelu(rx[i][1] + bv.y);
    float y2 = lrelu(rx[i][2] + bv.z);
    float y3 = lrelu(rx[i][3] + bv.w);
    if (HALF_OUT) {
      __half2* dst = (__half2*)((__half*)Yv + (size_t)gr * 128 + c0);
      dst[0] = __floats2half2_rn(y0, y1);
      dst[1] = __floats2half2_rn(y2, y3);
    } else {
      float4* dst = (float4*)((float*)Yv + (size_t)gr * 128 + c0);
      *dst = make_float4(y0, y1, y2, y3);
    }
  }
}

// ================= pooling: block per graph =================
__global__ __launch_bounds__(256) void k_pool(const float* __restrict__ H,
                                              const int* __restrict__ gstart,
                                              float* __restrict__ pooled) {
  __shared__ float lds[256];
  int g = blockIdx.x, t = threadIdx.x;
  int s = gstart[g], e = gstart[g + 1];
  int f = t & 127, half = t >> 7;
  float acc = 0.0f;
  for (int i = s + half; i < e; i += 2) acc += H[(size_t)i * 128 + f];
  lds[t] = acc;
  __syncthreads();
  if (t < 128) {
    float v = lds[t] + lds[t + 128];
    pooled[(size_t)g * 128 + t] = v / fmaxf((float)(e - s), 1.0f);
  }
}

// ================= MLP head =================
__global__ __launch_bounds__(128) void k_mlp(const float* __restrict__ pooled,
                                             const float* __restrict__ gfeat,
                                             const float* __restrict__ Wg, const float* __restrict__ bg,
                                             const float* __restrict__ Wf, const float* __restrict__ bf,
                                             const float* __restrict__ Wm1, const float* __restrict__ bm1,
                                             const float* __restrict__ Wm2, const float* __restrict__ bm2,
                                             float* __restrict__ out) {
  __shared__ float p[128], q[32], a[256], red[2];
  int g = blockIdx.x, t = threadIdx.x;
  p[t] = pooled[(size_t)g * 128 + t];
  if (t < 32) q[t] = gfeat[(size_t)g * 32 + t];
  __syncthreads();
  float acc = bg[t];
  for (int m = 0; m < 128; ++m) acc += p[m] * Wg[m * 128 + t];
  float acc2 = bf[t];
  for (int m = 0; m < 32; ++m) acc2 += q[m] * Wf[m * 128 + t];
  a[t] = lrelu(acc);
  a[128 + t] = lrelu(acc2);
  __syncthreads();
  float z = bm1[t];
  for (int k = 0; k < 256; ++k) z += a[k] * Wm1[k * 128 + t];
  z = lrelu(z);
  float v = z * Wm2[t];
#pragma unroll
  for (int off = 32; off; off >>= 1) v += __shfl_down(v, off);
  if ((t & 63) == 0) red[t >> 6] = v;
  __syncthreads();
  if (t == 0) out[g] = red[0] + red[1] + bm2[0];
}

extern "C" void kernel_launch(void* const* d_in, const int* in_sizes, int n_in,
                              void* d_out, int out_size, void* d_ws, size_t ws_size,
                              hipStream_t stream) {
  const float* x     = (const float*)d_in[0];
  const int*   ei    = (const int*)d_in[1];
  const int*   batch = (const int*)d_in[2];
  const float* gfeat = (const float*)d_in[3];
  const float* W1 = (const float*)d_in[4];
  const float* b1 = (const float*)d_in[5];
  const float* W2 = (const float*)d_in[6];
  const float* b2 = (const float*)d_in[7];
  const float* Wg = (const float*)d_in[8];
  const float* bg = (const float*)d_in[9];
  const float* Wf = (const float*)d_in[10];
  const float* bf = (const float*)d_in[11];
  const float* Wm1 = (const float*)d_in[12];
  const float* bm1 = (const float*)d_in[13];
  const float* Wm2 = (const float*)d_in[14];
  const float* bm2 = (const float*)d_in[15];
  float* out = (float*)d_out;

  const int N = in_sizes[0] / 64;
  const int E = in_sizes[1] / 2;
  const int G = in_sizes[3] / 32;
  const int* row = ei;
  const int* col = ei + E;

  // ---- workspace layout ----
  char* w = (char*)d_ws;
  size_t off = 0;
  auto alloc = [&](size_t bytes) {
    void* p = w + off;
    off = (off + bytes + 255) & ~(size_t)255;
    return p;
  };
  int*   degi     = (int*)alloc((size_t)N * 4);
  int*   rowstart = (int*)alloc((size_t)(N + 1) * 4);
  float* dinv     = (float*)alloc((size_t)N * 4);
  int*   bsums    = (int*)alloc(64 * 4);
  int*   gstart   = (int*)alloc((size_t)(G + 1) * 4);
  float* pooled   = (float*)alloc((size_t)G * 128 * 4);
  int*   csr_src  = (int*)alloc((size_t)E * 4);
  float* csr_w    = (float*)alloc((size_t)E * 4);
  __half* h1h     = (__half*)alloc((size_t)N * 128 * 2);   // fp16 h1
  // big region (N*128*4): P2 overlaps [xh | A64], both dead before agg128 writes
  char*  region   = (char*)alloc((size_t)N * 128 * 4);
  __half* xh      = (__half*)region;                        // N*64 fp16
  float*  A64     = (float*)(region + ((size_t)N * 64 * 2 + 255 & ~(size_t)255));  // N*64 fp32
  float*  P2      = (float*)region;                         // N*128 fp32 (agg128 out, gemm2 in/out)
  (void)ws_size;

  hipMemsetAsync(degi, 0, (size_t)N * 4, stream);

  // CSR build
  const int nblk = (N + 2047) / 2048;
  k_hist<<<(E + 255) / 256, 256, 0, stream>>>(col, degi, E);
  k_scan1<<<nblk, 256, 0, stream>>>(degi, rowstart, bsums, N);
  k_scan2<<<1, 64, 0, stream>>>(bsums, nblk);
  k_scan3<<<(N + 255) / 256, 256, 0, stream>>>(degi, rowstart, bsums, dinv, N);
  k_fill<<<(E + 255) / 256, 256, 0, stream>>>(row, col, dinv, degi, csr_src, csr_w, E);

  // graph boundaries
  k_gbound<<<(N + 255) / 256, 256, 0, stream>>>(batch, gstart, N, G);

  // x -> fp16
  const size_t total4 = (size_t)N * 16;  // N*64/4
  k_cvt_x<<<(int)((total4 + 255) / 256), 256, 0, stream>>>(x, xh, total4);

  const int aggGrid = (N * 64 + 255) / 256;

  // layer 1: aggregate (fp16 gather) in 64-dim, then GEMM -> fp16 h1
  k_agg64h<<<aggGrid, 256, 0, stream>>>(rowstart, csr_src, csr_w, dinv, x, xh, A64, N);
  k_gemm_rt<64, true><<<(N + 31) / 32, 256, 0, stream>>>(A64, W1, b1, h1h, N);

  // layer 2: aggregate h1 (fp16 gather) -> P2, then GEMM in-place -> P2
  k_agg128h<<<aggGrid, 256, 0, stream>>>(rowstart, csr_src, csr_w, dinv, h1h, P2, N);
  k_gemm_rt<128, false><<<(N + 31) / 32, 256, 0, stream>>>(P2, W2, b2, P2, N);

  // pooling + MLP head
  k_pool<<<G, 256, 0, stream>>>(P2, gstart, pooled);
  k_mlp<<<G, 128, 0, stream>>>(pooled, gfeat, Wg, bg, Wf, bf, Wm1, bm1, Wm2, bm2, out);
}

// Round 6
// 430.184 us; speedup vs baseline: 14.0808x; 1.1311x over previous
//
#include <hip/hip_runtime.h>
#include <hip/hip_fp16.h>

#define BW   128    // bucket width in nodes (pow2)
#define BSH  7
#define BCAP 2560   // edges capacity per bucket (mean ~2046 at N=100k,E=1.6M; 11 sigma headroom)

__device__ __forceinline__ float lrelu(float v) { return v >= 0.0f ? v : 0.01f * v; }

// ============ pass 1: bucket scatter (claims are time-ordered -> local writes) ============
__global__ __launch_bounds__(256) void k_bucket(const int* __restrict__ row,
                                                const int* __restrict__ col,
                                                int* __restrict__ bcur,
                                                int2* __restrict__ bedges, int E) {
  int e = blockIdx.x * 256 + threadIdx.x;
  if (e >= E) return;
  int r = row[e], c = col[e];
  int b = c >> BSH;
  int pos = atomicAdd(&bcur[b * 16], 1);  // 64B-padded counters
  if (pos < BCAP) bedges[(size_t)b * BCAP + pos] = make_int2(r, c);
}

// ============ scan bucket counts (NB <= 1024), single block ============
__global__ void k_scanb(const int* __restrict__ bcur, int* __restrict__ bstart, int NB) {
  __shared__ int lds[1024];
  int t = threadIdx.x;
  int v = (t < NB) ? bcur[t * 16] : 0;
  lds[t] = v;
  __syncthreads();
  for (int off = 1; off < 1024; off <<= 1) {
    int x = (t >= off) ? lds[t - off] : 0;
    __syncthreads();
    lds[t] += x;
    __syncthreads();
  }
  if (t < NB) bstart[t] = (t > 0) ? lds[t - 1] : 0;
}

// ============ pass 3a: per-bucket LDS histogram -> rowstart, dinv ============
__global__ __launch_bounds__(256) void k_rows(const int* __restrict__ bcur,
                                              const int* __restrict__ bstart,
                                              const int2* __restrict__ bedges,
                                              int* __restrict__ rowstart,
                                              float* __restrict__ dinv, int N) {
  __shared__ int hist[BW];
  __shared__ int sc[BW];
  int b = blockIdx.x, t = threadIdx.x;
  int cnt = min(bcur[b * 16], BCAP);
  int base = bstart[b];
  if (t < BW) hist[t] = 0;
  __syncthreads();
  const int2* be = bedges + (size_t)b * BCAP;
  for (int i = t; i < cnt; i += 256) atomicAdd(&hist[be[i].y & (BW - 1)], 1);
  __syncthreads();
  if (t < BW) sc[t] = hist[t];
  __syncthreads();
  for (int off = 1; off < BW; off <<= 1) {
    int x = 0;
    if (t < BW && t >= off) x = sc[t - off];
    __syncthreads();
    if (t < BW) sc[t] += x;
    __syncthreads();
  }
  int node = (b << BSH) + t;
  if (t < BW && node < N) {
    rowstart[node + 1] = base + sc[t];  // inclusive scan = end of node's segment
    dinv[node] = rsqrtf((float)hist[t] + 1.0f);
  }
  if (b == 0 && t == 0) rowstart[0] = 0;
}

// ============ pass 3b: per-bucket CSR fill {src, w}; dest region ~16KB (L2-local) ============
__global__ __launch_bounds__(256) void k_fill2(const int* __restrict__ bcur,
                                               const int* __restrict__ bstart,
                                               const int2* __restrict__ bedges,
                                               const int* __restrict__ rowstart,
                                               const float* __restrict__ dinv,
                                               int2* __restrict__ csr, int N) {
  __shared__ int cur[BW];
  __shared__ float dv[BW];
  int b = blockIdx.x, t = threadIdx.x;
  int cnt = min(bcur[b * 16], BCAP);
  int node = (b << BSH) + t;
  if (t < BW) {
    cur[t] = (node < N) ? rowstart[node] : 0;
    dv[t] = (node < N) ? dinv[node] : 0.0f;
  }
  __syncthreads();
  const int2* be = bedges + (size_t)b * BCAP;
  for (int i = t; i < cnt; i += 256) {
    int2 e = be[i];
    int lc = e.y & (BW - 1);
    int pos = atomicAdd(&cur[lc], 1);
    float w = dinv[e.x] * dv[lc];
    csr[pos] = make_int2(e.x, __float_as_int(w));
  }
}

// ============ graph boundaries (batch sorted) ============
__global__ __launch_bounds__(256) void k_gbound(const int* __restrict__ batch,
                                                int* __restrict__ gstart, int N, int G) {
  int i = blockIdx.x * 256 + threadIdx.x;
  if (i >= N) return;
  int b = batch[i];
  int prev = (i == 0) ? -1 : batch[i - 1];
  for (int g = prev + 1; g <= b; ++g) gstart[g] = i;
  if (i == N - 1)
    for (int g = b + 1; g <= G; ++g) gstart[g] = N;
}

// ============ x fp32 -> fp16 ============
__global__ __launch_bounds__(256) void k_cvt_x(const float* __restrict__ X,
                                               __half* __restrict__ Xh, size_t total4) {
  size_t i = (size_t)(blockIdx.x * 256 + threadIdx.x);
  if (i >= total4) return;
  float4 v = *(const float4*)&X[i * 4];
  __half2* dst = (__half2*)&Xh[i * 4];
  dst[0] = __floats2half2_rn(v.x, v.y);
  dst[1] = __floats2half2_rn(v.z, v.w);
}

// ============ gather-aggregate (linear, fp16 sources, int2 csr) ============
__global__ __launch_bounds__(256) void k_agg64h(const int* __restrict__ rowstart,
                                                const int2* __restrict__ csr,
                                                const float* __restrict__ dinv,
                                                const float* __restrict__ X,
                                                const __half* __restrict__ Xh,
                                                float* __restrict__ O, int N) {
  int wid = (blockIdx.x * 256 + threadIdx.x) >> 6;
  int lane = threadIdx.x & 63;
  if (wid >= N) return;
  int s = rowstart[wid], e = rowstart[wid + 1];
  float dc = dinv[wid];
  float acc = X[(size_t)wid * 64 + lane] * dc * dc;  // self loop (fp32)
#pragma unroll 4
  for (int i = s; i < e; ++i) {
    int2 ew = csr[i];
    acc += __half2float(Xh[(size_t)ew.x * 64 + lane]) * __int_as_float(ew.y);
  }
  O[(size_t)wid * 64 + lane] = acc;
}

__global__ __launch_bounds__(256) void k_agg128h(const int* __restrict__ rowstart,
                                                 const int2* __restrict__ csr,
                                                 const float* __restrict__ dinv,
                                                 const __half* __restrict__ H,
                                                 float* __restrict__ O, int N) {
  int wid = (blockIdx.x * 256 + threadIdx.x) >> 6;
  int lane = threadIdx.x & 63;
  if (wid >= N) return;
  int s = rowstart[wid], e = rowstart[wid + 1];
  float dc = dinv[wid];
  const __half2* Hv = (const __half2*)H;
  float2 hs = __half22float2(Hv[(size_t)wid * 64 + lane]);
  float2 acc;
  acc.x = hs.x * dc * dc;
  acc.y = hs.y * dc * dc;
#pragma unroll 4
  for (int i = s; i < e; ++i) {
    int2 ew = csr[i];
    float w = __int_as_float(ew.y);
    float2 h = __half22float2(Hv[(size_t)ew.x * 64 + lane]);
    acc.x += h.x * w;
    acc.y += h.y * w;
  }
  ((float2*)O)[(size_t)wid * 64 + lane] = acc;
}

// ============ GEMM + bias + LeakyReLU, register-tiled (in-place safe) ============
template <int K, bool HALF_OUT>
__global__ __launch_bounds__(256) void k_gemm_rt(const float* __restrict__ X,
                                                 const float* __restrict__ W,
                                                 const float* __restrict__ bias,
                                                 void* __restrict__ Yv, int N) {
  __shared__ float Xs[K * 32];
  const int t = threadIdx.x;
  const int row0 = blockIdx.x * 32;
  for (int i = t; i < 32 * K; i += 256) {
    int r = i / K, k = i % K;
    int gr = row0 + r;
    float v = (gr < N) ? X[(size_t)gr * K + k] : 0.0f;
    Xs[(k << 5) + ((((r >> 2) ^ (k & 7))) << 2) + (r & 3)] = v;
  }
  __syncthreads();
  const int tcol = t & 31, trow = t >> 5;
  const int c0 = tcol << 2;
  float a0x = 0, a0y = 0, a0z = 0, a0w = 0;
  float a1x = 0, a1y = 0, a1z = 0, a1w = 0;
  float a2x = 0, a2y = 0, a2z = 0, a2w = 0;
  float a3x = 0, a3y = 0, a3z = 0, a3w = 0;
#pragma unroll 4
  for (int k = 0; k < K; ++k) {
    float4 xv = *(const float4*)&Xs[(k << 5) + ((trow ^ (k & 7)) << 2)];
    float4 wv = *(const float4*)&W[k * 128 + c0];
    a0x += xv.x * wv.x; a0y += xv.x * wv.y; a0z += xv.x * wv.z; a0w += xv.x * wv.w;
    a1x += xv.y * wv.x; a1y += xv.y * wv.y; a1z += xv.y * wv.z; a1w += xv.y * wv.w;
    a2x += xv.z * wv.x; a2y += xv.z * wv.y; a2z += xv.z * wv.z; a2w += xv.z * wv.w;
    a3x += xv.w * wv.x; a3y += xv.w * wv.y; a3z += xv.w * wv.z; a3w += xv.w * wv.w;
  }
  float4 bv = *(const float4*)&bias[c0];
  float rx[4][4] = {{a0x, a0y, a0z, a0w},
                    {a1x, a1y, a1z, a1w},
                    {a2x, a2y, a2z, a2w},
                    {a3x, a3y, a3z, a3w}};
#pragma unroll
  for (int i = 0; i < 4; ++i) {
    int gr = row0 + (trow << 2) + i;
    if (gr >= N) break;
    float y0 = lrelu(rx[i][0] + bv.x);
    float y1 = lrelu(rx[i][1] + bv.y);
    float y2 = lrelu(rx[i][2] + bv.z);
    float y3 = lrelu(rx[i][3] + bv.w);
    if (HALF_OUT) {
      __half2* dst = (__half2*)((__half*)Yv + (size_t)gr * 128 + c0);
      dst[0] = __floats2half2_rn(y0, y1);
      dst[1] = __floats2half2_rn(y2, y3);
    } else {
      float4* dst = (float4*)((float*)Yv + (size_t)gr * 128 + c0);
      *dst = make_float4(y0, y1, y2, y3);
    }
  }
}

// ============ pooling: block per graph ============
__global__ __launch_bounds__(256) void k_pool(const float* __restrict__ H,
                                              const int* __restrict__ gstart,
                                              float* __restrict__ pooled) {
  __shared__ float lds[256];
  int g = blockIdx.x, t = threadIdx.x;
  int s = gstart[g], e = gstart[g + 1];
  int f = t & 127, half = t >> 7;
  float acc = 0.0f;
  for (int i = s + half; i < e; i += 2) acc += H[(size_t)i * 128 + f];
  lds[t] = acc;
  __syncthreads();
  if (t < 128) {
    float v = lds[t] + lds[t + 128];
    pooled[(size_t)g * 128 + t] = v / fmaxf((float)(e - s), 1.0f);
  }
}

// ============ MLP head ============
__global__ __launch_bounds__(128) void k_mlp(const float* __restrict__ pooled,
                                             const float* __restrict__ gfeat,
                                             const float* __restrict__ Wg, const float* __restrict__ bg,
                                             const float* __restrict__ Wf, const float* __restrict__ bf,
                                             const float* __restrict__ Wm1, const float* __restrict__ bm1,
                                             const float* __restrict__ Wm2, const float* __restrict__ bm2,
                                             float* __restrict__ out) {
  __shared__ float p[128], q[32], a[256], red[2];
  int g = blockIdx.x, t = threadIdx.x;
  p[t] = pooled[(size_t)g * 128 + t];
  if (t < 32) q[t] = gfeat[(size_t)g * 32 + t];
  __syncthreads();
  float acc = bg[t];
  for (int m = 0; m < 128; ++m) acc += p[m] * Wg[m * 128 + t];
  float acc2 = bf[t];
  for (int m = 0; m < 32; ++m) acc2 += q[m] * Wf[m * 128 + t];
  a[t] = lrelu(acc);
  a[128 + t] = lrelu(acc2);
  __syncthreads();
  float z = bm1[t];
  for (int k = 0; k < 256; ++k) z += a[k] * Wm1[k * 128 + t];
  z = lrelu(z);
  float v = z * Wm2[t];
#pragma unroll
  for (int off = 32; off; off >>= 1) v += __shfl_down(v, off);
  if ((t & 63) == 0) red[t >> 6] = v;
  __syncthreads();
  if (t == 0) out[g] = red[0] + red[1] + bm2[0];
}

extern "C" void kernel_launch(void* const* d_in, const int* in_sizes, int n_in,
                              void* d_out, int out_size, void* d_ws, size_t ws_size,
                              hipStream_t stream) {
  const float* x     = (const float*)d_in[0];
  const int*   ei    = (const int*)d_in[1];
  const int*   batch = (const int*)d_in[2];
  const float* gfeat = (const float*)d_in[3];
  const float* W1 = (const float*)d_in[4];
  const float* b1 = (const float*)d_in[5];
  const float* W2 = (const float*)d_in[6];
  const float* b2 = (const float*)d_in[7];
  const float* Wg = (const float*)d_in[8];
  const float* bg = (const float*)d_in[9];
  const float* Wf = (const float*)d_in[10];
  const float* bf = (const float*)d_in[11];
  const float* Wm1 = (const float*)d_in[12];
  const float* bm1 = (const float*)d_in[13];
  const float* Wm2 = (const float*)d_in[14];
  const float* bm2 = (const float*)d_in[15];
  float* out = (float*)d_out;

  const int N = in_sizes[0] / 64;
  const int E = in_sizes[1] / 2;
  const int G = in_sizes[3] / 32;
  const int* row = ei;
  const int* col = ei + E;
  const int NB = (N + BW - 1) >> BSH;  // buckets (<=1024 for N<=131072)

  // ---- workspace layout ----
  char* w = (char*)d_ws;
  size_t off = 0;
  auto alloc = [&](size_t bytes) {
    void* p = w + off;
    off = (off + bytes + 255) & ~(size_t)255;
    return p;
  };
  int*   bcur     = (int*)alloc((size_t)NB * 16 * 4);  // padded cursors
  int*   bstart   = (int*)alloc((size_t)NB * 4);
  int*   rowstart = (int*)alloc((size_t)(N + 1) * 4);
  float* dinv     = (float*)alloc((size_t)N * 4);
  int*   gstart   = (int*)alloc((size_t)(G + 1) * 4);
  float* pooled   = (float*)alloc((size_t)G * 128 * 4);
  int2*  csr      = (int2*)alloc((size_t)E * 8);
  __half* h1h     = (__half*)alloc((size_t)N * 128 * 2);   // fp16 h1
  // big region (N*128*4): xh | A64; bedges aliases A64 (dead before agg64h writes A64); P2 = whole region
  char*  region   = (char*)alloc((size_t)N * 128 * 4);
  __half* xh      = (__half*)region;                                                 // N*64 fp16
  size_t a64off   = ((size_t)N * 64 * 2 + 255) & ~(size_t)255;
  float*  A64     = (float*)(region + a64off);                                       // N*64 fp32
  int2*   bedges  = (int2*)(region + a64off);                                        // NB*BCAP int2 (16MB <= 25.6MB)
  float*  P2      = (float*)region;                                                  // N*128 fp32
  (void)ws_size;

  hipMemsetAsync(bcur, 0, (size_t)NB * 16 * 4, stream);

  // CSR build via bucket counting-sort
  k_bucket<<<(E + 255) / 256, 256, 0, stream>>>(row, col, bcur, bedges, E);
  k_scanb<<<1, 1024, 0, stream>>>(bcur, bstart, NB);
  k_rows<<<NB, 256, 0, stream>>>(bcur, bstart, bedges, rowstart, dinv, N);
  k_fill2<<<NB, 256, 0, stream>>>(bcur, bstart, bedges, rowstart, dinv, csr, N);

  // graph boundaries
  k_gbound<<<(N + 255) / 256, 256, 0, stream>>>(batch, gstart, N, G);

  // x -> fp16
  const size_t total4 = (size_t)N * 16;
  k_cvt_x<<<(int)((total4 + 255) / 256), 256, 0, stream>>>(x, xh, total4);

  const int aggGrid = (N * 64 + 255) / 256;

  // layer 1: aggregate (fp16 gather) in 64-dim, then GEMM -> fp16 h1
  k_agg64h<<<aggGrid, 256, 0, stream>>>(rowstart, csr, dinv, x, xh, A64, N);
  k_gemm_rt<64, true><<<(N + 31) / 32, 256, 0, stream>>>(A64, W1, b1, h1h, N);

  // layer 2: aggregate h1 (fp16 gather) -> P2, then GEMM in-place
  k_agg128h<<<aggGrid, 256, 0, stream>>>(rowstart, csr, dinv, h1h, P2, N);
  k_gemm_rt<128, false><<<(N + 31) / 32, 256, 0, stream>>>(P2, W2, b2, P2, N);

  // pooling + MLP head
  k_pool<<<G, 256, 0, stream>>>(P2, gstart, pooled);
  k_mlp<<<G, 128, 0, stream>>>(pooled, gfeat, Wg, bg, Wf, bf, Wm1, bm1, Wm2, bm2, out);
}

// Round 7
// 400.032 us; speedup vs baseline: 15.1422x; 1.0754x over previous
//
#include <hip/hip_runtime.h>
#include <hip/hip_fp16.h>

#define CBW  1024   // coarse bucket width in nodes (pow2)
#define CBSH 10
#define CCAP 20480  // per-bucket capacity (mean ~16.3k at N=100k,E=1.6M; +32 sigma)

__device__ __forceinline__ float lrelu(float v) { return v >= 0.0f ? v : 0.01f * v; }

// ============ pass 1: histogram-partition (run-claimed, write-owner = one block) ============
__global__ __launch_bounds__(256) void k_part(const int* __restrict__ row,
                                              const int* __restrict__ col,
                                              int* __restrict__ bcur,
                                              int2* __restrict__ bedges, int E, int NB) {
  __shared__ int hist[128];
  __shared__ int gbase[128];
  const int t = threadIdx.x;
  const int base = blockIdx.x * 2048 + t * 8;
  int r[8], c[8];
  if (base + 8 <= E) {
    int4 r0 = *(const int4*)&row[base], r1 = *(const int4*)&row[base + 4];
    int4 c0 = *(const int4*)&col[base], c1 = *(const int4*)&col[base + 4];
    r[0] = r0.x; r[1] = r0.y; r[2] = r0.z; r[3] = r0.w;
    r[4] = r1.x; r[5] = r1.y; r[6] = r1.z; r[7] = r1.w;
    c[0] = c0.x; c[1] = c0.y; c[2] = c0.z; c[3] = c0.w;
    c[4] = c1.x; c[5] = c1.y; c[6] = c1.z; c[7] = c1.w;
  } else {
#pragma unroll
    for (int j = 0; j < 8; ++j) {
      bool ok = (base + j) < E;
      r[j] = ok ? row[base + j] : 0;
      c[j] = ok ? col[base + j] : -1;
    }
  }
  if (t < 128) hist[t] = 0;
  __syncthreads();
#pragma unroll
  for (int j = 0; j < 8; ++j)
    if (c[j] >= 0) atomicAdd(&hist[c[j] >> CBSH], 1);
  __syncthreads();
  if (t < NB && hist[t] > 0) gbase[t] = atomicAdd(&bcur[t * 16], hist[t]);
  __syncthreads();
  if (t < 128) hist[t] = 0;  // reuse as local cursor
  __syncthreads();
#pragma unroll
  for (int j = 0; j < 8; ++j) {
    if (c[j] < 0) continue;
    int b = c[j] >> CBSH;
    int lp = atomicAdd(&hist[b], 1);
    int p = gbase[b] + lp;
    if (p < CCAP) bedges[(size_t)b * CCAP + p] = make_int2(r[j], c[j]);
  }
}

// ============ scan bucket counts (NB <= 1024), single block ============
__global__ void k_scanb(const int* __restrict__ bcur, int* __restrict__ bstart, int NB) {
  __shared__ int lds[1024];
  int t = threadIdx.x;
  int v = (t < NB) ? min(bcur[t * 16], CCAP) : 0;
  lds[t] = v;
  __syncthreads();
  for (int off = 1; off < 1024; off <<= 1) {
    int x = (t >= off) ? lds[t - off] : 0;
    __syncthreads();
    lds[t] += x;
    __syncthreads();
  }
  if (t < NB) bstart[t] = (t > 0) ? lds[t - 1] : 0;
}

// ============ pass 2: per-bucket LDS histogram -> rowstart, dinv ============
__global__ __launch_bounds__(256) void k_rows(const int* __restrict__ bcur,
                                              const int* __restrict__ bstart,
                                              const int2* __restrict__ bedges,
                                              int* __restrict__ rowstart,
                                              float* __restrict__ dinv, int N) {
  __shared__ int hist[CBW];
  __shared__ int tsum[256];
  int b = blockIdx.x, t = threadIdx.x;
  int cnt = min(bcur[b * 16], CCAP);
  int gbs = bstart[b];
  for (int i = t; i < CBW; i += 256) hist[i] = 0;
  __syncthreads();
  const int2* be = bedges + (size_t)b * CCAP;
  for (int i = t; i < cnt; i += 256) atomicAdd(&hist[be[i].y & (CBW - 1)], 1);
  __syncthreads();
  int h0 = hist[t * 4], h1 = hist[t * 4 + 1], h2 = hist[t * 4 + 2], h3 = hist[t * 4 + 3];
  int s0 = h0, s1 = s0 + h1, s2 = s1 + h2, s3 = s2 + h3;
  tsum[t] = s3;
  __syncthreads();
  for (int off = 1; off < 256; off <<= 1) {
    int x = (t >= off) ? tsum[t - off] : 0;
    __syncthreads();
    tsum[t] += x;
    __syncthreads();
  }
  int prefix = (t > 0) ? tsum[t - 1] : 0;
  int node0 = (b << CBSH) + t * 4;
  int ends[4] = {s0, s1, s2, s3};
  int hs[4] = {h0, h1, h2, h3};
#pragma unroll
  for (int j = 0; j < 4; ++j) {
    int node = node0 + j;
    if (node < N) {
      rowstart[node + 1] = gbs + prefix + ends[j];
      dinv[node] = rsqrtf((float)hs[j] + 1.0f);
    }
  }
  if (b == 0 && t == 0) rowstart[0] = 0;
}

// ============ pass 3: per-bucket CSR fill {src, w}; dest region ~130KB (L2-local) ============
__global__ __launch_bounds__(256) void k_fill2(const int* __restrict__ bcur,
                                               const int* __restrict__ bstart,
                                               const int2* __restrict__ bedges,
                                               const int* __restrict__ rowstart,
                                               const float* __restrict__ dinv,
                                               int2* __restrict__ csr, int N) {
  __shared__ int cur[CBW];
  __shared__ float dv[CBW];
  int b = blockIdx.x, t = threadIdx.x;
  int cnt = min(bcur[b * 16], CCAP);
  for (int i = t; i < CBW; i += 256) {
    int node = (b << CBSH) + i;
    cur[i] = (node < N) ? rowstart[node] : 0;
    dv[i] = (node < N) ? dinv[node] : 0.0f;
  }
  __syncthreads();
  const int2* be = bedges + (size_t)b * CCAP;
  for (int i = t; i < cnt; i += 256) {
    int2 e = be[i];
    int lc = e.y & (CBW - 1);
    int pos = atomicAdd(&cur[lc], 1);
    float w = dinv[e.x] * dv[lc];
    csr[pos] = make_int2(e.x, __float_as_int(w));
  }
}

// ============ graph boundaries (batch sorted) ============
__global__ __launch_bounds__(256) void k_gbound(const int* __restrict__ batch,
                                                int* __restrict__ gstart, int N, int G) {
  int i = blockIdx.x * 256 + threadIdx.x;
  if (i >= N) return;
  int b = batch[i];
  int prev = (i == 0) ? -1 : batch[i - 1];
  for (int g = prev + 1; g <= b; ++g) gstart[g] = i;
  if (i == N - 1)
    for (int g = b + 1; g <= G; ++g) gstart[g] = N;
}

// ============ x fp32 -> fp16 ============
__global__ __launch_bounds__(256) void k_cvt_x(const float* __restrict__ X,
                                               __half* __restrict__ Xh, size_t total4) {
  size_t i = (size_t)(blockIdx.x * 256 + threadIdx.x);
  if (i >= total4) return;
  float4 v = *(const float4*)&X[i * 4];
  __half2* dst = (__half2*)&Xh[i * 4];
  dst[0] = __floats2half2_rn(v.x, v.y);
  dst[1] = __floats2half2_rn(v.z, v.w);
}

// ============ gather-aggregate (linear, fp16 sources, int2 csr) ============
__global__ __launch_bounds__(256) void k_agg64h(const int* __restrict__ rowstart,
                                                const int2* __restrict__ csr,
                                                const float* __restrict__ dinv,
                                                const float* __restrict__ X,
                                                const __half* __restrict__ Xh,
                                                float* __restrict__ O, int N) {
  int wid = (blockIdx.x * 256 + threadIdx.x) >> 6;
  int lane = threadIdx.x & 63;
  if (wid >= N) return;
  int s = rowstart[wid], e = rowstart[wid + 1];
  float dc = dinv[wid];
  float acc = X[(size_t)wid * 64 + lane] * dc * dc;  // self loop (fp32)
#pragma unroll 4
  for (int i = s; i < e; ++i) {
    int2 ew = csr[i];
    acc += __half2float(Xh[(size_t)ew.x * 64 + lane]) * __int_as_float(ew.y);
  }
  O[(size_t)wid * 64 + lane] = acc;
}

__global__ __launch_bounds__(256) void k_agg128h(const int* __restrict__ rowstart,
                                                 const int2* __restrict__ csr,
                                                 const float* __restrict__ dinv,
                                                 const __half* __restrict__ H,
                                                 float* __restrict__ O, int N) {
  int wid = (blockIdx.x * 256 + threadIdx.x) >> 6;
  int lane = threadIdx.x & 63;
  if (wid >= N) return;
  int s = rowstart[wid], e = rowstart[wid + 1];
  float dc = dinv[wid];
  const __half2* Hv = (const __half2*)H;
  float2 hs = __half22float2(Hv[(size_t)wid * 64 + lane]);
  float2 acc;
  acc.x = hs.x * dc * dc;
  acc.y = hs.y * dc * dc;
#pragma unroll 4
  for (int i = s; i < e; ++i) {
    int2 ew = csr[i];
    float w = __int_as_float(ew.y);
    float2 h = __half22float2(Hv[(size_t)ew.x * 64 + lane]);
    acc.x += h.x * w;
    acc.y += h.y * w;
  }
  ((float2*)O)[(size_t)wid * 64 + lane] = acc;
}

// ============ GEMM + bias + LeakyReLU, register-tiled (in-place safe) ============
template <int K, bool HALF_OUT>
__global__ __launch_bounds__(256) void k_gemm_rt(const float* __restrict__ X,
                                                 const float* __restrict__ W,
                                                 const float* __restrict__ bias,
                                                 void* __restrict__ Yv, int N) {
  __shared__ float Xs[K * 32];
  const int t = threadIdx.x;
  const int row0 = blockIdx.x * 32;
  for (int i = t; i < 32 * K; i += 256) {
    int r = i / K, k = i % K;
    int gr = row0 + r;
    float v = (gr < N) ? X[(size_t)gr * K + k] : 0.0f;
    Xs[(k << 5) + ((((r >> 2) ^ (k & 7))) << 2) + (r & 3)] = v;
  }
  __syncthreads();
  const int tcol = t & 31, trow = t >> 5;
  const int c0 = tcol << 2;
  float a0x = 0, a0y = 0, a0z = 0, a0w = 0;
  float a1x = 0, a1y = 0, a1z = 0, a1w = 0;
  float a2x = 0, a2y = 0, a2z = 0, a2w = 0;
  float a3x = 0, a3y = 0, a3z = 0, a3w = 0;
#pragma unroll 4
  for (int k = 0; k < K; ++k) {
    float4 xv = *(const float4*)&Xs[(k << 5) + ((trow ^ (k & 7)) << 2)];
    float4 wv = *(const float4*)&W[k * 128 + c0];
    a0x += xv.x * wv.x; a0y += xv.x * wv.y; a0z += xv.x * wv.z; a0w += xv.x * wv.w;
    a1x += xv.y * wv.x; a1y += xv.y * wv.y; a1z += xv.y * wv.z; a1w += xv.y * wv.w;
    a2x += xv.z * wv.x; a2y += xv.z * wv.y; a2z += xv.z * wv.z; a2w += xv.z * wv.w;
    a3x += xv.w * wv.x; a3y += xv.w * wv.y; a3z += xv.w * wv.z; a3w += xv.w * wv.w;
  }
  float4 bv = *(const float4*)&bias[c0];
  float rx[4][4] = {{a0x, a0y, a0z, a0w},
                    {a1x, a1y, a1z, a1w},
                    {a2x, a2y, a2z, a2w},
                    {a3x, a3y, a3z, a3w}};
#pragma unroll
  for (int i = 0; i < 4; ++i) {
    int gr = row0 + (trow << 2) + i;
    if (gr >= N) break;
    float y0 = lrelu(rx[i][0] + bv.x);
    float y1 = lrelu(rx[i][1] + bv.y);
    float y2 = lrelu(rx[i][2] + bv.z);
    float y3 = lrelu(rx[i][3] + bv.w);
    if (HALF_OUT) {
      __half2* dst = (__half2*)((__half*)Yv + (size_t)gr * 128 + c0);
      dst[0] = __floats2half2_rn(y0, y1);
      dst[1] = __floats2half2_rn(y2, y3);
    } else {
      float4* dst = (float4*)((float*)Yv + (size_t)gr * 128 + c0);
      *dst = make_float4(y0, y1, y2, y3);
    }
  }
}

// ============ pooling: block per graph ============
__global__ __launch_bounds__(256) void k_pool(const float* __restrict__ H,
                                              const int* __restrict__ gstart,
                                              float* __restrict__ pooled) {
  __shared__ float lds[256];
  int g = blockIdx.x, t = threadIdx.x;
  int s = gstart[g], e = gstart[g + 1];
  int f = t & 127, half = t >> 7;
  float acc = 0.0f;
  for (int i = s + half; i < e; i += 2) acc += H[(size_t)i * 128 + f];
  lds[t] = acc;
  __syncthreads();
  if (t < 128) {
    float v = lds[t] + lds[t + 128];
    pooled[(size_t)g * 128 + t] = v / fmaxf((float)(e - s), 1.0f);
  }
}

// ============ MLP head ============
__global__ __launch_bounds__(128) void k_mlp(const float* __restrict__ pooled,
                                             const float* __restrict__ gfeat,
                                             const float* __restrict__ Wg, const float* __restrict__ bg,
                                             const float* __restrict__ Wf, const float* __restrict__ bf,
                                             const float* __restrict__ Wm1, const float* __restrict__ bm1,
                                             const float* __restrict__ Wm2, const float* __restrict__ bm2,
                                             float* __restrict__ out) {
  __shared__ float p[128], q[32], a[256], red[2];
  int g = blockIdx.x, t = threadIdx.x;
  p[t] = pooled[(size_t)g * 128 + t];
  if (t < 32) q[t] = gfeat[(size_t)g * 32 + t];
  __syncthreads();
  float acc = bg[t];
  for (int m = 0; m < 128; ++m) acc += p[m] * Wg[m * 128 + t];
  float acc2 = bf[t];
  for (int m = 0; m < 32; ++m) acc2 += q[m] * Wf[m * 128 + t];
  a[t] = lrelu(acc);
  a[128 + t] = lrelu(acc2);
  __syncthreads();
  float z = bm1[t];
  for (int k = 0; k < 256; ++k) z += a[k] * Wm1[k * 128 + t];
  z = lrelu(z);
  float v = z * Wm2[t];
#pragma unroll
  for (int off = 32; off; off >>= 1) v += __shfl_down(v, off);
  if ((t & 63) == 0) red[t >> 6] = v;
  __syncthreads();
  if (t == 0) out[g] = red[0] + red[1] + bm2[0];
}

extern "C" void kernel_launch(void* const* d_in, const int* in_sizes, int n_in,
                              void* d_out, int out_size, void* d_ws, size_t ws_size,
                              hipStream_t stream) {
  const float* x     = (const float*)d_in[0];
  const int*   ei    = (const int*)d_in[1];
  const int*   batch = (const int*)d_in[2];
  const float* gfeat = (const float*)d_in[3];
  const float* W1 = (const float*)d_in[4];
  const float* b1 = (const float*)d_in[5];
  const float* W2 = (const float*)d_in[6];
  const float* b2 = (const float*)d_in[7];
  const float* Wg = (const float*)d_in[8];
  const float* bg = (const float*)d_in[9];
  const float* Wf = (const float*)d_in[10];
  const float* bf = (const float*)d_in[11];
  const float* Wm1 = (const float*)d_in[12];
  const float* bm1 = (const float*)d_in[13];
  const float* Wm2 = (const float*)d_in[14];
  const float* bm2 = (const float*)d_in[15];
  float* out = (float*)d_out;

  const int N = in_sizes[0] / 64;
  const int E = in_sizes[1] / 2;
  const int G = in_sizes[3] / 32;
  const int* row = ei;
  const int* col = ei + E;
  const int NB = (N + CBW - 1) >> CBSH;  // coarse buckets (98 for N=100k)

  // ---- workspace layout ----
  char* w = (char*)d_ws;
  size_t off = 0;
  auto alloc = [&](size_t bytes) {
    void* p = w + off;
    off = (off + bytes + 255) & ~(size_t)255;
    return p;
  };
  int*   bcur     = (int*)alloc((size_t)NB * 16 * 4);  // padded counters
  int*   bstart   = (int*)alloc((size_t)NB * 4);
  int*   rowstart = (int*)alloc((size_t)(N + 1) * 4);
  float* dinv     = (float*)alloc((size_t)N * 4);
  int*   gstart   = (int*)alloc((size_t)(G + 1) * 4);
  float* pooled   = (float*)alloc((size_t)G * 128 * 4);
  int2*  csr      = (int2*)alloc((size_t)E * 8);
  __half* h1h     = (__half*)alloc((size_t)N * 128 * 2);   // fp16 h1
  // big region (N*128*4): xh | A64; bedges aliases A64 (dead before agg64h); P2 = whole region
  char*  region   = (char*)alloc((size_t)N * 128 * 4);
  __half* xh      = (__half*)region;                                   // N*64 fp16
  size_t a64off   = ((size_t)N * 64 * 2 + 255) & ~(size_t)255;
  float*  A64     = (float*)(region + a64off);                         // N*64 fp32
  int2*   bedges  = (int2*)(region + a64off);                          // NB*CCAP int2 (~16MB)
  float*  P2      = (float*)region;                                    // N*128 fp32
  (void)ws_size;

  hipMemsetAsync(bcur, 0, (size_t)NB * 16 * 4, stream);

  // CSR build via histogram-partition counting sort
  k_part<<<(E + 2047) / 2048, 256, 0, stream>>>(row, col, bcur, bedges, E, NB);
  k_scanb<<<1, 1024, 0, stream>>>(bcur, bstart, NB);
  k_rows<<<NB, 256, 0, stream>>>(bcur, bstart, bedges, rowstart, dinv, N);
  k_fill2<<<NB, 256, 0, stream>>>(bcur, bstart, bedges, rowstart, dinv, csr, N);

  // graph boundaries
  k_gbound<<<(N + 255) / 256, 256, 0, stream>>>(batch, gstart, N, G);

  // x -> fp16
  const size_t total4 = (size_t)N * 16;
  k_cvt_x<<<(int)((total4 + 255) / 256), 256, 0, stream>>>(x, xh, total4);

  const int aggGrid = (N * 64 + 255) / 256;

  // layer 1: aggregate (fp16 gather) in 64-dim, then GEMM -> fp16 h1
  k_agg64h<<<aggGrid, 256, 0, stream>>>(rowstart, csr, dinv, x, xh, A64, N);
  k_gemm_rt<64, true><<<(N + 31) / 32, 256, 0, stream>>>(A64, W1, b1, h1h, N);

  // layer 2: aggregate h1 (fp16 gather) -> P2, then GEMM in-place
  k_agg128h<<<aggGrid, 256, 0, stream>>>(rowstart, csr, dinv, h1h, P2, N);
  k_gemm_rt<128, false><<<(N + 31) / 32, 256, 0, stream>>>(P2, W2, b2, P2, N);

  // pooling + MLP head
  k_pool<<<G, 256, 0, stream>>>(P2, gstart, pooled);
  k_mlp<<<G, 128, 0, stream>>>(pooled, gfeat, Wg, bg, Wf, bf, Wm1, bm1, Wm2, bm2, out);
}

// Round 8
// 321.072 us; speedup vs baseline: 18.8660x; 1.2459x over previous
//
#include <hip/hip_runtime.h>
#include <hip/hip_fp16.h>

#define CBW  1024
#define CBSH 10
#define CCAP 20480

typedef _Float16 f16x8 __attribute__((ext_vector_type(8)));
typedef float f32x4 __attribute__((ext_vector_type(4)));

__device__ __forceinline__ float lrelu(float v) { return v >= 0.0f ? v : 0.01f * v; }

// ============ pass 1: histogram-partition counting sort ============
__global__ __launch_bounds__(256) void k_part(const int* __restrict__ row,
                                              const int* __restrict__ col,
                                              int* __restrict__ bcur,
                                              int2* __restrict__ bedges, int E, int NB) {
  __shared__ int hist[128];
  __shared__ int gbase[128];
  const int t = threadIdx.x;
  const int base = blockIdx.x * 2048 + t * 8;
  int r[8], c[8];
  if (base + 8 <= E) {
    int4 r0 = *(const int4*)&row[base], r1 = *(const int4*)&row[base + 4];
    int4 c0 = *(const int4*)&col[base], c1 = *(const int4*)&col[base + 4];
    r[0] = r0.x; r[1] = r0.y; r[2] = r0.z; r[3] = r0.w;
    r[4] = r1.x; r[5] = r1.y; r[6] = r1.z; r[7] = r1.w;
    c[0] = c0.x; c[1] = c0.y; c[2] = c0.z; c[3] = c0.w;
    c[4] = c1.x; c[5] = c1.y; c[6] = c1.z; c[7] = c1.w;
  } else {
#pragma unroll
    for (int j = 0; j < 8; ++j) {
      bool ok = (base + j) < E;
      r[j] = ok ? row[base + j] : 0;
      c[j] = ok ? col[base + j] : -1;
    }
  }
  if (t < 128) hist[t] = 0;
  __syncthreads();
#pragma unroll
  for (int j = 0; j < 8; ++j)
    if (c[j] >= 0) atomicAdd(&hist[c[j] >> CBSH], 1);
  __syncthreads();
  if (t < NB && hist[t] > 0) gbase[t] = atomicAdd(&bcur[t * 16], hist[t]);
  __syncthreads();
  if (t < 128) hist[t] = 0;  // reuse as local cursor
  __syncthreads();
#pragma unroll
  for (int j = 0; j < 8; ++j) {
    if (c[j] < 0) continue;
    int b = c[j] >> CBSH;
    int lp = atomicAdd(&hist[b], 1);
    int p = gbase[b] + lp;
    if (p < CCAP) bedges[(size_t)b * CCAP + p] = make_int2(r[j], c[j]);
  }
}

// ============ scan bucket counts ============
__global__ void k_scanb(const int* __restrict__ bcur, int* __restrict__ bstart, int NB) {
  __shared__ int lds[1024];
  int t = threadIdx.x;
  int v = (t < NB) ? min(bcur[t * 16], CCAP) : 0;
  lds[t] = v;
  __syncthreads();
  for (int off = 1; off < 1024; off <<= 1) {
    int x = (t >= off) ? lds[t - off] : 0;
    __syncthreads();
    lds[t] += x;
    __syncthreads();
  }
  if (t < NB) bstart[t] = (t > 0) ? lds[t - 1] : 0;
}

// ============ pass 2: per-bucket LDS histogram -> rowstart, dinv ============
__global__ __launch_bounds__(256) void k_rows(const int* __restrict__ bcur,
                                              const int* __restrict__ bstart,
                                              const int2* __restrict__ bedges,
                                              int* __restrict__ rowstart,
                                              float* __restrict__ dinv, int N) {
  __shared__ int hist[CBW];
  __shared__ int tsum[256];
  int b = blockIdx.x, t = threadIdx.x;
  int cnt = min(bcur[b * 16], CCAP);
  int gbs = bstart[b];
  for (int i = t; i < CBW; i += 256) hist[i] = 0;
  __syncthreads();
  const int2* be = bedges + (size_t)b * CCAP;
  for (int i = t; i < cnt; i += 256) atomicAdd(&hist[be[i].y & (CBW - 1)], 1);
  __syncthreads();
  int h0 = hist[t * 4], h1 = hist[t * 4 + 1], h2 = hist[t * 4 + 2], h3 = hist[t * 4 + 3];
  int s0 = h0, s1 = s0 + h1, s2 = s1 + h2, s3 = s2 + h3;
  tsum[t] = s3;
  __syncthreads();
  for (int off = 1; off < 256; off <<= 1) {
    int x = (t >= off) ? tsum[t - off] : 0;
    __syncthreads();
    tsum[t] += x;
    __syncthreads();
  }
  int prefix = (t > 0) ? tsum[t - 1] : 0;
  int node0 = (b << CBSH) + t * 4;
  int ends[4] = {s0, s1, s2, s3};
  int hs[4] = {h0, h1, h2, h3};
#pragma unroll
  for (int j = 0; j < 4; ++j) {
    int node = node0 + j;
    if (node < N) {
      rowstart[node + 1] = gbs + prefix + ends[j];
      dinv[node] = rsqrtf((float)hs[j] + 1.0f);
    }
  }
  if (b == 0 && t == 0) rowstart[0] = 0;
}

// ============ pass 3: per-bucket CSR fill {src, w} ============
__global__ __launch_bounds__(256) void k_fill2(const int* __restrict__ bcur,
                                               const int* __restrict__ bstart,
                                               const int2* __restrict__ bedges,
                                               const int* __restrict__ rowstart,
                                               const float* __restrict__ dinv,
                                               int2* __restrict__ csr, int N) {
  __shared__ int cur[CBW];
  __shared__ float dv[CBW];
  int b = blockIdx.x, t = threadIdx.x;
  int cnt = min(bcur[b * 16], CCAP);
  for (int i = t; i < CBW; i += 256) {
    int node = (b << CBSH) + i;
    cur[i] = (node < N) ? rowstart[node] : 0;
    dv[i] = (node < N) ? dinv[node] : 0.0f;
  }
  __syncthreads();
  const int2* be = bedges + (size_t)b * CCAP;
  for (int i = t; i < cnt; i += 256) {
    int2 e = be[i];
    int lc = e.y & (CBW - 1);
    int pos = atomicAdd(&cur[lc], 1);
    float w = dinv[e.x] * dv[lc];
    csr[pos] = make_int2(e.x, __float_as_int(w));
  }
}

// ============ graph boundaries (batch sorted) ============
__global__ __launch_bounds__(256) void k_gbound(const int* __restrict__ batch,
                                                int* __restrict__ gstart, int N, int G) {
  int i = blockIdx.x * 256 + threadIdx.x;
  if (i >= N) return;
  int b = batch[i];
  int prev = (i == 0) ? -1 : batch[i - 1];
  for (int g = prev + 1; g <= b; ++g) gstart[g] = i;
  if (i == N - 1)
    for (int g = b + 1; g <= G; ++g) gstart[g] = N;
}

// ============ x fp32 -> fp16 ============
__global__ __launch_bounds__(256) void k_cvt_x(const float* __restrict__ X,
                                               __half* __restrict__ Xh, size_t total4) {
  size_t i = (size_t)(blockIdx.x * 256 + threadIdx.x);
  if (i >= total4) return;
  float4 v = *(const float4*)&X[i * 4];
  __half2* dst = (__half2*)&Xh[i * 4];
  dst[0] = __floats2half2_rn(v.x, v.y);
  dst[1] = __floats2half2_rn(v.z, v.w);
}

// ============ W fp32 -> fp16 MFMA B-fragment layout ============
// Wf[(((kc*8)+cb)*64 + l)*8 + i] = W[kc*32 + (l>>4)*8 + i][cb*16 + (l&15)]
__global__ __launch_bounds__(256) void k_cvtW(const float* __restrict__ W,
                                              __half* __restrict__ Wf, int K) {
  int idx = blockIdx.x * 256 + threadIdx.x;
  if (idx >= K * 128) return;
  int i = idx & 7, l = (idx >> 3) & 63, cb = (idx >> 9) & 7, kc = idx >> 12;
  int ks = kc * 32 + ((l >> 4) << 3) + i;
  int c = cb * 16 + (l & 15);
  Wf[idx] = __float2half(W[ks * 128 + c]);
}

// ============ gather-aggregate (fp16 in, fp16 out) ============
__global__ __launch_bounds__(256) void k_agg64h(const int* __restrict__ rowstart,
                                                const int2* __restrict__ csr,
                                                const float* __restrict__ dinv,
                                                const float* __restrict__ X,
                                                const __half* __restrict__ Xh,
                                                __half* __restrict__ O, int N) {
  int wid = (blockIdx.x * 256 + threadIdx.x) >> 6;
  int lane = threadIdx.x & 63;
  if (wid >= N) return;
  int s = rowstart[wid], e = rowstart[wid + 1];
  float dc = dinv[wid];
  float acc = X[(size_t)wid * 64 + lane] * dc * dc;  // self loop (fp32)
#pragma unroll 4
  for (int i = s; i < e; ++i) {
    int2 ew = csr[i];
    acc += __half2float(Xh[(size_t)ew.x * 64 + lane]) * __int_as_float(ew.y);
  }
  O[(size_t)wid * 64 + lane] = __float2half(acc);
}

__global__ __launch_bounds__(256) void k_agg128h(const int* __restrict__ rowstart,
                                                 const int2* __restrict__ csr,
                                                 const float* __restrict__ dinv,
                                                 const __half* __restrict__ H,
                                                 __half* __restrict__ O, int N) {
  int wid = (blockIdx.x * 256 + threadIdx.x) >> 6;
  int lane = threadIdx.x & 63;
  if (wid >= N) return;
  int s = rowstart[wid], e = rowstart[wid + 1];
  float dc = dinv[wid];
  const __half2* Hv = (const __half2*)H;
  float2 hs = __half22float2(Hv[(size_t)wid * 64 + lane]);
  float2 acc;
  acc.x = hs.x * dc * dc;
  acc.y = hs.y * dc * dc;
#pragma unroll 4
  for (int i = s; i < e; ++i) {
    int2 ew = csr[i];
    float w = __int_as_float(ew.y);
    float2 h = __half22float2(Hv[(size_t)ew.x * 64 + lane]);
    acc.x += h.x * w;
    acc.y += h.y * w;
  }
  ((__half2*)O)[(size_t)wid * 64 + lane] = __floats2half2_rn(acc.x, acc.y);
}

// ============ MFMA GEMM: Y[N,128] = lrelu(A[N,K]@W + b), fp16 in/out, fp32 acc ============
// block = 4 waves; wave computes 16 rows x 128 cols. No LDS.
// A-frag: lane l holds A[rowbase + (l&15)][kc*32 + (l>>4)*8 + i]  (16B, lanes sharing a row
//         cover one full 64B line -> fully coalesced).
// B-frag: precomputed Wf (16B/lane contiguous). C/D: row=(l>>4)*4+v, col=cb*16+(l&15).
template <int KC>  // K/32
__global__ __launch_bounds__(256) void k_gemm_mfma(const __half* __restrict__ A,
                                                   const __half* __restrict__ Wf,
                                                   const float* __restrict__ bias,
                                                   __half* __restrict__ Y, int N) {
  const int t = threadIdx.x;
  const int l = t & 63;
  const int lr = l & 15, lg = l >> 4;
  const int rowbase = blockIdx.x * 64 + (t >> 6) * 16;
  const int K = KC * 32;
  f32x4 acc[8];
#pragma unroll
  for (int cb = 0; cb < 8; ++cb) acc[cb] = (f32x4){0.f, 0.f, 0.f, 0.f};
  int arow = min(rowbase + lr, N - 1);
  const _Float16* Ap = (const _Float16*)A + (size_t)arow * K + lg * 8;
  const _Float16* Wp = (const _Float16*)Wf + (size_t)l * 8;
#pragma unroll
  for (int kc = 0; kc < KC; ++kc) {
    f16x8 a = *(const f16x8*)(Ap + kc * 32);
#pragma unroll
    for (int cb = 0; cb < 8; ++cb) {
      f16x8 b = *(const f16x8*)(Wp + (size_t)((kc * 8 + cb) * 64) * 8);
      acc[cb] = __builtin_amdgcn_mfma_f32_16x16x32_f16(a, b, acc[cb], 0, 0, 0);
    }
  }
#pragma unroll
  for (int cb = 0; cb < 8; ++cb) {
    int c = cb * 16 + lr;
    float bv = bias[c];
#pragma unroll
    for (int v = 0; v < 4; ++v) {
      int gr = rowbase + lg * 4 + v;
      if (gr < N) Y[(size_t)gr * 128 + c] = __float2half(lrelu(acc[cb][v] + bv));
    }
  }
}

// ============ pooling: block per graph, fp16 input ============
__global__ __launch_bounds__(256) void k_pool(const __half* __restrict__ H,
                                              const int* __restrict__ gstart,
                                              float* __restrict__ pooled) {
  __shared__ float2 lds[256];
  int g = blockIdx.x, t = threadIdx.x;
  int s = gstart[g], e = gstart[g + 1];
  int c2 = t & 63, q = t >> 6;
  const __half2* Hv = (const __half2*)H;
  float2 acc = make_float2(0.f, 0.f);
  for (int i = s + q; i < e; i += 4) {
    float2 h = __half22float2(Hv[(size_t)i * 64 + c2]);
    acc.x += h.x;
    acc.y += h.y;
  }
  lds[t] = acc;
  __syncthreads();
  if (t < 64) {
    float2 a = lds[t], b = lds[t + 64], c = lds[t + 128], d = lds[t + 192];
    float inv = 1.0f / fmaxf((float)(e - s), 1.0f);
    pooled[(size_t)g * 128 + t * 2]     = (a.x + b.x + c.x + d.x) * inv;
    pooled[(size_t)g * 128 + t * 2 + 1] = (a.y + b.y + c.y + d.y) * inv;
  }
}

// ============ MLP head ============
__global__ __launch_bounds__(128) void k_mlp(const float* __restrict__ pooled,
                                             const float* __restrict__ gfeat,
                                             const float* __restrict__ Wg, const float* __restrict__ bg,
                                             const float* __restrict__ Wf, const float* __restrict__ bf,
                                             const float* __restrict__ Wm1, const float* __restrict__ bm1,
                                             const float* __restrict__ Wm2, const float* __restrict__ bm2,
                                             float* __restrict__ out) {
  __shared__ float p[128], q[32], a[256], red[2];
  int g = blockIdx.x, t = threadIdx.x;
  p[t] = pooled[(size_t)g * 128 + t];
  if (t < 32) q[t] = gfeat[(size_t)g * 32 + t];
  __syncthreads();
  float acc = bg[t];
  for (int m = 0; m < 128; ++m) acc += p[m] * Wg[m * 128 + t];
  float acc2 = bf[t];
  for (int m = 0; m < 32; ++m) acc2 += q[m] * Wf[m * 128 + t];
  a[t] = lrelu(acc);
  a[128 + t] = lrelu(acc2);
  __syncthreads();
  float z = bm1[t];
  for (int k = 0; k < 256; ++k) z += a[k] * Wm1[k * 128 + t];
  z = lrelu(z);
  float v = z * Wm2[t];
#pragma unroll
  for (int off = 32; off; off >>= 1) v += __shfl_down(v, off);
  if ((t & 63) == 0) red[t >> 6] = v;
  __syncthreads();
  if (t == 0) out[g] = red[0] + red[1] + bm2[0];
}

extern "C" void kernel_launch(void* const* d_in, const int* in_sizes, int n_in,
                              void* d_out, int out_size, void* d_ws, size_t ws_size,
                              hipStream_t stream) {
  const float* x     = (const float*)d_in[0];
  const int*   ei    = (const int*)d_in[1];
  const int*   batch = (const int*)d_in[2];
  const float* gfeat = (const float*)d_in[3];
  const float* W1 = (const float*)d_in[4];
  const float* b1 = (const float*)d_in[5];
  const float* W2 = (const float*)d_in[6];
  const float* b2 = (const float*)d_in[7];
  const float* Wg = (const float*)d_in[8];
  const float* bg = (const float*)d_in[9];
  const float* Wf = (const float*)d_in[10];
  const float* bf = (const float*)d_in[11];
  const float* Wm1 = (const float*)d_in[12];
  const float* bm1 = (const float*)d_in[13];
  const float* Wm2 = (const float*)d_in[14];
  const float* bm2 = (const float*)d_in[15];
  float* out = (float*)d_out;

  const int N = in_sizes[0] / 64;
  const int E = in_sizes[1] / 2;
  const int G = in_sizes[3] / 32;
  const int* row = ei;
  const int* col = ei + E;
  const int NB = (N + CBW - 1) >> CBSH;

  // ---- workspace layout ----
  char* w = (char*)d_ws;
  size_t off = 0;
  auto alloc = [&](size_t bytes) {
    void* p = w + off;
    off = (off + bytes + 255) & ~(size_t)255;
    return p;
  };
  int*   bcur     = (int*)alloc((size_t)NB * 16 * 4);
  int*   bstart   = (int*)alloc((size_t)NB * 4);
  int*   rowstart = (int*)alloc((size_t)(N + 1) * 4);
  float* dinv     = (float*)alloc((size_t)N * 4);
  int*   gstart   = (int*)alloc((size_t)(G + 1) * 4);
  float* pooled   = (float*)alloc((size_t)G * 128 * 4);
  __half* Wf1     = (__half*)alloc((size_t)64 * 128 * 2);
  __half* Wf2     = (__half*)alloc((size_t)128 * 128 * 2);
  int2*  csr      = (int2*)alloc((size_t)E * 8);
  // regionA: h1h (N*128 fp16); xh (N*64 fp16) aliases its start (dead before gemm1 writes h1h)
  char*  regionA  = (char*)alloc((size_t)N * 128 * 2);
  __half* h1h     = (__half*)regionA;
  __half* xh      = (__half*)regionA;
  // regionB: A2h (N*128 fp16); bedges (NB*CCAP int2, ~16MB) aliases (dead before agg128h)
  char*  regionB  = (char*)alloc((size_t)N * 128 * 2 > (size_t)NB * CCAP * 8
                                     ? (size_t)N * 128 * 2 : (size_t)NB * CCAP * 8);
  __half* A2h     = (__half*)regionB;
  int2*   bedges  = (int2*)regionB;
  // regionC: h2h (N*128 fp16); A64h (N*64 fp16) aliases its start (dead before gemm2 writes h2h)
  char*  regionC  = (char*)alloc((size_t)N * 128 * 2);
  __half* h2h     = (__half*)regionC;
  __half* A64h    = (__half*)regionC;
  (void)ws_size;

  // NOTE on xh/h1h alias: agg64h reads xh and writes A64h (regionC); gemm1 then reads
  // A64h and writes h1h (regionA) — xh is dead by then. Same reasoning for the others.

  hipMemsetAsync(bcur, 0, (size_t)NB * 16 * 4, stream);

  // CSR build
  k_part<<<(E + 2047) / 2048, 256, 0, stream>>>(row, col, bcur, bedges, E, NB);
  k_scanb<<<1, 1024, 0, stream>>>(bcur, bstart, NB);
  k_rows<<<NB, 256, 0, stream>>>(bcur, bstart, bedges, rowstart, dinv, N);
  k_fill2<<<NB, 256, 0, stream>>>(bcur, bstart, bedges, rowstart, dinv, csr, N);

  // graph boundaries + weight fragment packs + x->fp16
  k_gbound<<<(N + 255) / 256, 256, 0, stream>>>(batch, gstart, N, G);
  k_cvtW<<<(64 * 128 + 255) / 256, 256, 0, stream>>>(W1, Wf1, 64);
  k_cvtW<<<(128 * 128 + 255) / 256, 256, 0, stream>>>(W2, Wf2, 128);
  const size_t total4 = (size_t)N * 16;
  k_cvt_x<<<(int)((total4 + 255) / 256), 256, 0, stream>>>(x, xh, total4);

  const int aggGrid = (N * 64 + 255) / 256;
  const int gemmGrid = (N + 63) / 64;

  // layer 1
  k_agg64h<<<aggGrid, 256, 0, stream>>>(rowstart, csr, dinv, x, xh, A64h, N);
  k_gemm_mfma<2><<<gemmGrid, 256, 0, stream>>>(A64h, Wf1, b1, h1h, N);

  // layer 2
  k_agg128h<<<aggGrid, 256, 0, stream>>>(rowstart, csr, dinv, h1h, A2h, N);
  k_gemm_mfma<4><<<gemmGrid, 256, 0, stream>>>(A2h, Wf2, b2, h2h, N);

  // pooling + MLP head
  k_pool<<<G, 256, 0, stream>>>(h2h, gstart, pooled);
  k_mlp<<<G, 128, 0, stream>>>(pooled, gfeat, Wg, bg, Wf, bf, Wm1, bm1, Wm2, bm2, out);
}